// Round 11
// baseline (587.615 us; speedup 1.0000x reference)
//
#include <hip/hip_runtime.h>

// Problem constants
#define Hh    8
#define DMm   512
#define HDd   64
#define CBc   32
#define SBs   64
#define WINSZ 512
#define TOPKk 16
#define NEGF  (-1e30f)
#define Bb    2
#define Ss    4096
#define NCc   128   // S/CB
#define NSs   64    // S/SB
#define SCALE 0.125f
#define PSC   0.18033688011112042f   // SCALE * log2(e): q pre-scale -> exp2 softmax

// Workspace layout (float offsets)
#define OFF_KL   ((size_t)4194304)    // f16 k_lo [bh][s][d]
#define OFF_O    ((size_t)12582912)   // ALIASED: x_hi/x_lo live here until k_cmp writes o
#define OFF_G    ((size_t)16777216)   // B*S*3 = 24576
#define OFF_KC   ((size_t)16801792)   // kc_hi/kc_lo f16 (2 x 131072 halves)
#define OFF_VC   ((size_t)16932864)   // vc^T f16 (131072 halves)
#define OFF_IMPB ((size_t)17063936)   // (unused; kept for layout stability)
#define OFF_SEL  ((size_t)17129472)   // B*H*NS*TOPK ints = 16384
#define OFF_QH   ((size_t)17145856)   // f16 q  [bh][s][d] (pre-scaled by PSC)
#define OFF_KH   ((size_t)19243008)   // f16 k_hi [bh][s][d]
#define OFF_VT   ((size_t)21340160)   // f16 v^T [bh][d][s]
#define OFF_WT   ((size_t)23437312)   // 7 x 131072 floats of f16 W^T (hi/lo)
#define OFF_QL   ((size_t)24354816)   // f16 q_lo [bh][s][d] (pre-scaled by PSC)
#define WS_FLOATS ((size_t)25403392)

// x_hi/x_lo alias the o region (o first written by k_cmp, after GEMMs)
#define OFF_XH   (OFF_O)
#define OFF_XL   (OFF_O + 2097152)

#define OFF_KCH  (OFF_KC)
#define OFF_KCL  (OFF_KC + 65536)
#define OFF_VCT  (OFF_VC)

typedef _Float16 f16;
typedef _Float16 f16x4 __attribute__((ext_vector_type(4)));
typedef _Float16 f16x8 __attribute__((ext_vector_type(8)));
typedef float    f32x4 __attribute__((ext_vector_type(4)));

__device__ __forceinline__ int swz(int row, int byteoff) {
    return byteoff ^ ((row & 7) << 4);   // spreads stride-128B rows across banks
}
__device__ __forceinline__ float fexp2(float x) {
    return __builtin_amdgcn_exp2f(x);    // v_exp_f32: D = 2^S0
}

// V LDS layout: per 32-key block, quads interleaved as {4lg, 16+4lg} so that a
// single b128 read at [ktp*64 + lg*16] yields keys {ktp*32+4lg+0..3, +16+0..3}
// (matches in-register P order for mfma_16x16x32). Write side: 2 x b64.
#define STAGE_V(Vbase, vd, row, c8) do {                                     \
    int q0_ = ((c8) & 3) * 2, q1_ = q0_ + 1;                                 \
    int col0_ = ((c8) >> 2) * 64 + (q0_ & 3) * 16 + (q0_ >> 2) * 8;          \
    int col1_ = ((c8) >> 2) * 64 + (q1_ & 3) * 16 + (q1_ >> 2) * 8;          \
    f16x4 lo_ = { (vd)[0], (vd)[1], (vd)[2], (vd)[3] };                      \
    f16x4 hi_ = { (vd)[4], (vd)[5], (vd)[6], (vd)[7] };                      \
    *(f16x4*)((Vbase) + swz(row, (row) * 128 + col0_)) = lo_;                \
    *(f16x4*)((Vbase) + swz(row, (row) * 128 + col1_)) = hi_;                \
} while (0)

// -------------------- K0a: fused x -> x_hi/x_lo + gate ------------------------
__global__ __launch_bounds__(256) void k_prep_xg(const float* __restrict__ x,
        const float* __restrict__ Wg, f16* __restrict__ xh, f16* __restrict__ xl,
        float* __restrict__ g)
{
    const int w = threadIdx.x >> 6, l = threadIdx.x & 63;
    const int row = blockIdx.x * 4 + w;        // 0..8191
    const int d0 = l * 8;
    const float* xr = x + (size_t)row * DMm + d0;
    float4 a = *(const float4*)(xr);
    float4 b = *(const float4*)(xr + 4);
    float xv[8] = { a.x, a.y, a.z, a.w, b.x, b.y, b.z, b.w };
    f16x8 h, lo;
#pragma unroll
    for (int j = 0; j < 8; ++j) {
        h[j] = (_Float16)xv[j];
        lo[j] = (_Float16)(xv[j] - (float)h[j]);
    }
    size_t base = (size_t)row * DMm + d0;
    *(f16x8*)(xh + base) = h;
    *(f16x8*)(xl + base) = lo;
    float s0 = 0.f, s1 = 0.f, s2 = 0.f;
#pragma unroll
    for (int j = 0; j < 8; ++j) {
        const float* wr = Wg + (size_t)(d0 + j) * 3;
        s0 += xv[j] * wr[0];
        s1 += xv[j] * wr[1];
        s2 += xv[j] * wr[2];
    }
#pragma unroll
    for (int off = 1; off < 64; off <<= 1) {
        s0 += __shfl_xor(s0, off);
        s1 += __shfl_xor(s1, off);
        s2 += __shfl_xor(s2, off);
    }
    if (l == 0) {
        g[(size_t)row * 3 + 0] = 1.f / (1.f + expf(-s0));
        g[(size_t)row * 3 + 1] = 1.f / (1.f + expf(-s1));
        g[(size_t)row * 3 + 2] = 1.f / (1.f + expf(-s2));
    }
}

// -------------------- K0b: W -> W^T hi/lo (f16) -------------------------------
__global__ __launch_bounds__(256) void k_prep_w(
        const float* __restrict__ Wq, const float* __restrict__ Wk,
        const float* __restrict__ Wv, const float* __restrict__ Wo,
        f16* __restrict__ wqh, f16* __restrict__ wql,
        f16* __restrict__ wkh, f16* __restrict__ wkl,
        f16* __restrict__ wvh, f16* __restrict__ wvl,
        f16* __restrict__ woh)
{
    const int k0 = blockIdx.x * 64;
    const int n0 = blockIdx.y * 64;
    const int z = blockIdx.z;
    const float* W = (z == 0) ? Wq : ((z == 1) ? Wk : ((z == 2) ? Wv : Wo));
    f16* dh = (z == 0) ? wqh : ((z == 1) ? wkh : ((z == 2) ? wvh : woh));
    f16* dl = (z == 0) ? wql : ((z == 1) ? wkl : ((z == 2) ? wvl : (f16*)0));
    __shared__ float T[64][68];
    const int tid = threadIdx.x;
    {
        int r = tid >> 2;
        int c16 = (tid & 3) * 16;
#pragma unroll
        for (int j = 0; j < 4; ++j) {
            float4 w4 = *(const float4*)(W + (size_t)(k0 + r) * DMm + n0 + c16 + j * 4);
            *(float4*)&T[r][c16 + j * 4] = w4;
        }
    }
    __syncthreads();
    {
        int n = tid >> 2;
        int k16 = (tid & 3) * 16;
        f16x8 h0, h1, l0, l1;
#pragma unroll
        for (int j = 0; j < 8; ++j) {
            float wv = T[k16 + j][n];
            h0[j] = (_Float16)wv; l0[j] = (_Float16)(wv - (float)h0[j]);
        }
#pragma unroll
        for (int j = 0; j < 8; ++j) {
            float wv = T[k16 + 8 + j][n];
            h1[j] = (_Float16)wv; l1[j] = (_Float16)(wv - (float)h1[j]);
        }
        size_t o = (size_t)(n0 + n) * DMm + k0 + k16;
        *(f16x8*)(dh + o) = h0;
        *(f16x8*)(dh + o + 8) = h1;
        if (dl) { *(f16x8*)(dl + o) = l0; *(f16x8*)(dl + o + 8) = l1; }
    }
}

// -------------------- K1: merged q/k/v projection GEMMs -----------------------
__global__ __launch_bounds__(256) void k_gemm3(
        const f16* __restrict__ xh, const f16* __restrict__ xl,
        const f16* __restrict__ wqh, const f16* __restrict__ wql,
        const f16* __restrict__ wkh, const f16* __restrict__ wkl,
        const f16* __restrict__ wvh,
        f16* __restrict__ qh, f16* __restrict__ ql,
        f16* __restrict__ kh, f16* __restrict__ kl,
        f16* __restrict__ vt)
{
    const int z = blockIdx.z;
    const int m0 = blockIdx.x * 128;
    const int n0 = blockIdx.y * 64;
    const int tid = threadIdx.x;
    const int w = tid >> 6, l = tid & 63;
    const int lr = l & 15, lg = l >> 4;
    const int wm = w >> 1, wn = w & 1;

    __shared__ f16 As[2][128 * 40];
    __shared__ f16 Bs[2][64 * 40];

    f32x4 acc[4][2];
#pragma unroll
    for (int mf = 0; mf < 4; ++mf)
#pragma unroll
        for (int nf = 0; nf < 2; ++nf) acc[mf][nf] = (f32x4){0.f, 0.f, 0.f, 0.f};

    const int ar = tid >> 1, ac = (tid & 1) * 16;
    const int bn = tid >> 2, bc = (tid & 3) * 8;

    if (z == 2) {
        // ---- v path: plain f16, swapped-operand MFMA -> transposed out ------
        for (int k0 = 0; k0 < DMm; k0 += 32) {
            {
                const f16* src = xh + (size_t)(m0 + ar) * DMm + k0 + ac;
                *(f16x8*)&As[0][ar * 40 + ac] = *(const f16x8*)src;
                *(f16x8*)&As[0][ar * 40 + ac + 8] = *(const f16x8*)(src + 8);
                const f16* srcb = wvh + (size_t)(n0 + bn) * DMm + k0 + bc;
                *(f16x8*)&Bs[0][bn * 40 + bc] = *(const f16x8*)srcb;
            }
            __syncthreads();
            f16x8 ahf[4], bhf[2];
#pragma unroll
            for (int mf = 0; mf < 4; ++mf)
                ahf[mf] = *(const f16x8*)&As[0][(wm * 64 + mf * 16 + lr) * 40 + lg * 8];
#pragma unroll
            for (int nf = 0; nf < 2; ++nf)
                bhf[nf] = *(const f16x8*)&Bs[0][(wn * 32 + nf * 16 + lr) * 40 + lg * 8];
#pragma unroll
            for (int mf = 0; mf < 4; ++mf)
#pragma unroll
                for (int nf = 0; nf < 2; ++nf)
                    acc[mf][nf] = __builtin_amdgcn_mfma_f32_16x16x32_f16(bhf[nf], ahf[mf], acc[mf][nf], 0, 0, 0);
            __syncthreads();
        }
        const int h = n0 >> 6;
#pragma unroll
        for (int mf = 0; mf < 4; ++mf)
#pragma unroll
            for (int nf = 0; nf < 2; ++nf)
#pragma unroll
                for (int rg = 0; rg < 4; ++rg) {
                    int n = n0 + wn * 32 + nf * 16 + 4 * lg + rg;   // d (global)
                    int m = m0 + wm * 64 + mf * 16 + lr;            // s (incl batch)
                    int b = m >> 12, s = m & 4095;
                    vt[(((size_t)(b * Hh + h)) * HDd + (n & 63)) * Ss + s] =
                        (f16)acc[mf][nf][rg];
                }
        return;
    }

    // ---- q/k path: split-f16 (3-product, fp32-grade) ------------------------
    const f16* Bh = z ? wkh : wqh;
    const f16* Bl = z ? wkl : wql;
    f16* Ch = z ? kh : qh;
    f16* Cl = z ? kl : ql;
    const float cscale = z ? 1.f : PSC;

    for (int k0 = 0; k0 < DMm; k0 += 32) {
        {
            const f16* src = xh + (size_t)(m0 + ar) * DMm + k0 + ac;
            *(f16x8*)&As[0][ar * 40 + ac] = *(const f16x8*)src;
            *(f16x8*)&As[0][ar * 40 + ac + 8] = *(const f16x8*)(src + 8);
            const f16* src2 = xl + (size_t)(m0 + ar) * DMm + k0 + ac;
            *(f16x8*)&As[1][ar * 40 + ac] = *(const f16x8*)src2;
            *(f16x8*)&As[1][ar * 40 + ac + 8] = *(const f16x8*)(src2 + 8);
        }
        {
            const f16* src = Bh + (size_t)(n0 + bn) * DMm + k0 + bc;
            *(f16x8*)&Bs[0][bn * 40 + bc] = *(const f16x8*)src;
            const f16* src2 = Bl + (size_t)(n0 + bn) * DMm + k0 + bc;
            *(f16x8*)&Bs[1][bn * 40 + bc] = *(const f16x8*)src2;
        }
        __syncthreads();

        f16x8 ahf[4], alf[4], bhf[2], blf[2];
#pragma unroll
        for (int mf = 0; mf < 4; ++mf) {
            int row = wm * 64 + mf * 16 + lr;
            ahf[mf] = *(const f16x8*)&As[0][row * 40 + lg * 8];
            alf[mf] = *(const f16x8*)&As[1][row * 40 + lg * 8];
        }
#pragma unroll
        for (int nf = 0; nf < 2; ++nf) {
            int row = wn * 32 + nf * 16 + lr;
            bhf[nf] = *(const f16x8*)&Bs[0][row * 40 + lg * 8];
            blf[nf] = *(const f16x8*)&Bs[1][row * 40 + lg * 8];
        }
#pragma unroll
        for (int mf = 0; mf < 4; ++mf)
#pragma unroll
            for (int nf = 0; nf < 2; ++nf) {
                acc[mf][nf] = __builtin_amdgcn_mfma_f32_16x16x32_f16(ahf[mf], bhf[nf], acc[mf][nf], 0, 0, 0);
                acc[mf][nf] = __builtin_amdgcn_mfma_f32_16x16x32_f16(ahf[mf], blf[nf], acc[mf][nf], 0, 0, 0);
                acc[mf][nf] = __builtin_amdgcn_mfma_f32_16x16x32_f16(alf[mf], bhf[nf], acc[mf][nf], 0, 0, 0);
            }
        __syncthreads();
    }

#pragma unroll
    for (int mf = 0; mf < 4; ++mf)
#pragma unroll
        for (int nf = 0; nf < 2; ++nf)
#pragma unroll
            for (int rg = 0; rg < 4; ++rg) {
                int m = m0 + wm * 64 + mf * 16 + 4 * lg + rg;
                int n = n0 + wn * 32 + nf * 16 + lr;
                int b = m >> 12, s = m & 4095;
                int h = n >> 6, d = n & 63;
                size_t o = (((size_t)(b * Hh + h)) * Ss + s) * HDd + d;
                float vs = acc[mf][nf][rg] * cscale;
                f16 hv = (f16)vs;
                Ch[o] = hv;
                Cl[o] = (f16)(vs - (float)hv);
            }
}

// -------------------- K1c: outproj GEMM (fp32 A staged, plain f16) ------------
__global__ __launch_bounds__(256) void k_outproj(const float* __restrict__ Af,
        const f16* __restrict__ Bh, float* __restrict__ Cf)
{
    const int m0 = blockIdx.x * 128;
    const int n0 = blockIdx.y * 64;
    const int tid = threadIdx.x;
    const int w = tid >> 6, l = tid & 63;
    const int lr = l & 15, lg = l >> 4;
    const int wm = w >> 1, wn = w & 1;

    __shared__ f16 As[128 * 40];
    __shared__ f16 Bs[64 * 40];

    f32x4 acc[4][2];
#pragma unroll
    for (int mf = 0; mf < 4; ++mf)
#pragma unroll
        for (int nf = 0; nf < 2; ++nf) acc[mf][nf] = (f32x4){0.f, 0.f, 0.f, 0.f};

    const int ar = tid >> 1, ac = (tid & 1) * 16;
    const int bn = tid >> 2, bc = (tid & 3) * 8;

    for (int k0 = 0; k0 < DMm; k0 += 32) {
        {
            const float* src = Af + (size_t)(m0 + ar) * DMm + k0 + ac;
            float4 a0 = *(const float4*)(src);
            float4 a1 = *(const float4*)(src + 4);
            float4 a2 = *(const float4*)(src + 8);
            float4 a3 = *(const float4*)(src + 12);
            f16x8 h0, h1;
            h0[0] = (_Float16)a0.x; h0[1] = (_Float16)a0.y; h0[2] = (_Float16)a0.z; h0[3] = (_Float16)a0.w;
            h0[4] = (_Float16)a1.x; h0[5] = (_Float16)a1.y; h0[6] = (_Float16)a1.z; h0[7] = (_Float16)a1.w;
            h1[0] = (_Float16)a2.x; h1[1] = (_Float16)a2.y; h1[2] = (_Float16)a2.z; h1[3] = (_Float16)a2.w;
            h1[4] = (_Float16)a3.x; h1[5] = (_Float16)a3.y; h1[6] = (_Float16)a3.z; h1[7] = (_Float16)a3.w;
            *(f16x8*)&As[ar * 40 + ac] = h0;
            *(f16x8*)&As[ar * 40 + ac + 8] = h1;
            const f16* srcb = Bh + (size_t)(n0 + bn) * DMm + k0 + bc;
            *(f16x8*)&Bs[bn * 40 + bc] = *(const f16x8*)srcb;
        }
        __syncthreads();
        f16x8 ahf[4], bhf[2];
#pragma unroll
        for (int mf = 0; mf < 4; ++mf)
            ahf[mf] = *(const f16x8*)&As[(wm * 64 + mf * 16 + lr) * 40 + lg * 8];
#pragma unroll
        for (int nf = 0; nf < 2; ++nf)
            bhf[nf] = *(const f16x8*)&Bs[(wn * 32 + nf * 16 + lr) * 40 + lg * 8];
#pragma unroll
        for (int mf = 0; mf < 4; ++mf)
#pragma unroll
            for (int nf = 0; nf < 2; ++nf)
                acc[mf][nf] = __builtin_amdgcn_mfma_f32_16x16x32_f16(ahf[mf], bhf[nf], acc[mf][nf], 0, 0, 0);
        __syncthreads();
    }
#pragma unroll
    for (int mf = 0; mf < 4; ++mf)
#pragma unroll
        for (int nf = 0; nf < 2; ++nf)
#pragma unroll
            for (int rg = 0; rg < 4; ++rg) {
                int m = m0 + wm * 64 + mf * 16 + 4 * lg + rg;
                int n = n0 + wn * 32 + nf * 16 + lr;
                Cf[(size_t)m * DMm + n] = acc[mf][nf][rg];
            }
}

// -------------------- K3: mean-pool from f16 k_hi/k_lo and vt -----------------
__global__ __launch_bounds__(256) void k_pool(const f16* __restrict__ kh,
        const f16* __restrict__ kl, const f16* __restrict__ vt,
        f16* __restrict__ kch, f16* __restrict__ kcl, f16* __restrict__ vct)
{
    int idx = blockIdx.x * 256 + threadIdx.x;  // B*H*NC*HD = 131072
    int bh = idx >> 13;
    {
        int d = idx & 63;
        int n = (idx >> 6) & 127;
        const f16* kp = kh + ((size_t)bh * Ss + n * CBc) * HDd + d;
        const f16* lp = kl + ((size_t)bh * Ss + n * CBc) * HDd + d;
        float sk = 0.f;
        for (int t = 0; t < CBc; ++t)
            sk += (float)kp[(size_t)t * HDd] + (float)lp[(size_t)t * HDd];
        float mk = sk * (1.f / CBc);
        f16 h = (f16)mk;
        kch[idx] = h;
        kcl[idx] = (f16)(mk - (float)h);
    }
    {
        int vd = (idx >> 7) & 63;
        int vn = idx & 127;
        const f16* vp = vt + ((size_t)bh * HDd + vd) * Ss + vn * CBc;
        float sv = 0.f;
#pragma unroll
        for (int j = 0; j < 4; ++j) {
            f16x8 v8 = *(const f16x8*)(vp + j * 8);
#pragma unroll
            for (int e = 0; e < 8; ++e) sv += (float)v8[e];
        }
        vct[((size_t)bh * HDd + vd) * NCc + vn] = (f16)(sv * (1.f / CBc));
    }
}

// -------------------- K4: compressed attention + importance + FUSED top-k -----
// Block (qb,bh) computes the full 64-wide importance row locally, so top-k runs
// here on wave 0 (16-step 64-lane argmax, lowest-index tie-break == old k_topk).
__global__ __launch_bounds__(256) void k_cmp(const f16* __restrict__ qh,
        const f16* __restrict__ ql, const f16* __restrict__ kch,
        const f16* __restrict__ kcl, const f16* __restrict__ vct,
        const float* __restrict__ g, int* __restrict__ sel, float* __restrict__ o)
{
    const int qb = blockIdx.x;   // 0..63
    const int bh = blockIdx.y;   // 0..15
    const int b = bh >> 3, h = bh & 7;
    const int q0 = qb * 64;
    const int tid = threadIdx.x;
    const int w = tid >> 6, l = tid & 63;
    const int lr = l & 15, lg = l >> 4;

    __shared__ __align__(16) char smem[51456];
    float* Pm = (float*)smem;                       // [64][132] fp32 exp2 values
    char* U = smem + 33792;                         // 16KB union: {KCh,KCl} / {VCt,Ps}
    float* red2 = (float*)(smem + 33792 + 16384);   // 256 floats
    float* rinv = (float*)(smem + 51200);           // 64 floats

    const int NCT = (qb <= 30) ? 1 : 2;
    const int ncols = NCT * 64;

    f16x8 qfh0, qfh1, qfl0, qfl1;
    {
        size_t qoff = ((size_t)bh * Ss + q0 + w * 16 + lr) * HDd + lg * 8;
        qfh0 = *(const f16x8*)(qh + qoff);
        qfh1 = *(const f16x8*)(qh + qoff + 32);
        qfl0 = *(const f16x8*)(ql + qoff);
        qfl1 = *(const f16x8*)(ql + qoff + 32);
    }

    for (int ct = 0; ct < NCT; ++ct) {
        __syncthreads();
#pragma unroll
        for (int p = 0; p < 2; ++p) {
            int idx = tid + p * 256;
            int row = idx >> 3;           // chunk 0..63
            int c8 = idx & 7;
            size_t src = ((size_t)bh * NCc + ct * 64 + row) * HDd + c8 * 8;
            *(f16x8*)(U + swz(row, row * 128 + c8 * 16)) = *(const f16x8*)(kch + src);
            *(f16x8*)(U + 8192 + swz(row, row * 128 + c8 * 16)) = *(const f16x8*)(kcl + src);
        }
        __syncthreads();
#pragma unroll
        for (int kt = 0; kt < 4; ++kt) {
            int krow = kt * 16 + lr;
            f16x8 bh0 = *(const f16x8*)(U + swz(krow, krow * 128 + lg * 16));
            f16x8 bh1 = *(const f16x8*)(U + swz(krow, krow * 128 + lg * 16 + 64));
            f16x8 bl0 = *(const f16x8*)(U + 8192 + swz(krow, krow * 128 + lg * 16));
            f16x8 bl1 = *(const f16x8*)(U + 8192 + swz(krow, krow * 128 + lg * 16 + 64));
            f32x4 c = (f32x4){0.f, 0.f, 0.f, 0.f};
            c = __builtin_amdgcn_mfma_f32_16x16x32_f16(qfh0, bh0, c, 0, 0, 0);
            c = __builtin_amdgcn_mfma_f32_16x16x32_f16(qfh1, bh1, c, 0, 0, 0);
            c = __builtin_amdgcn_mfma_f32_16x16x32_f16(qfh0, bl0, c, 0, 0, 0);
            c = __builtin_amdgcn_mfma_f32_16x16x32_f16(qfh1, bl1, c, 0, 0, 0);
            c = __builtin_amdgcn_mfma_f32_16x16x32_f16(qfl0, bh0, c, 0, 0, 0);
            c = __builtin_amdgcn_mfma_f32_16x16x32_f16(qfl1, bh1, c, 0, 0, 0);
            int n = ct * 64 + kt * 16 + lr;
#pragma unroll
            for (int rg = 0; rg < 4; ++rg) {
                int row = w * 16 + 4 * lg + rg;
                int s = q0 + row;
                bool valid = (32 * n + 31 <= s);
                Pm[row * 132 + n] = valid ? c[rg] : NEGF;   // log2-domain score
            }
        }
    }
    __syncthreads();

    {
        int r = tid >> 2;
        int l4 = tid & 3;
        float m = NEGF;
        for (int c = l4; c < ncols; c += 4) m = fmaxf(m, Pm[r * 132 + c]);
        m = fmaxf(m, __shfl_xor(m, 1));
        m = fmaxf(m, __shfl_xor(m, 2));
        float sum = 0.f;
        if (m > NEGF * 0.5f) {
            for (int c = l4; c < ncols; c += 4) {
                float sv = Pm[r * 132 + c];
                float p = (sv <= NEGF * 0.5f) ? 0.f : fexp2(sv - m);
                Pm[r * 132 + c] = p;    // unnormalized
                sum += p;
            }
        } else {
            for (int c = l4; c < ncols; c += 4) Pm[r * 132 + c] = 0.f;
        }
        sum += __shfl_xor(sum, 1);
        sum += __shfl_xor(sum, 2);
        if (l4 == 0) rinv[r] = (sum > 0.f) ? 1.f / sum : 0.f;
    }
    __syncthreads();

    {
        float part = 0.f;
#pragma unroll
        for (int rr = 0; rr < 16; ++rr) {
            int qq = w * 16 + rr;
            int c = 2 * l;
            if (c < ncols) {
                float2 pv2 = *(const float2*)&Pm[qq * 132 + c];
                part += (pv2.x + pv2.y) * rinv[qq];
            }
        }
        red2[w * 64 + l] = part;
    }
    __syncthreads();
    if (tid < 64) {
        float tot = red2[tid] + red2[64 + tid] + red2[128 + tid] + red2[192 + tid];
        // fused top-k (wave 0): identical values + tie-break as old k_topk
        int j = tid;
        float v = tot;
        if (j > qb) v = NEGF;
        if (j == qb) v += 1e9f;
        int* selrow = sel + ((size_t)bh * NSs + qb) * TOPKk;
        for (int t = 0; t < TOPKk; ++t) {
            float bv = v; int bi = j;
#pragma unroll
            for (int off = 1; off < 64; off <<= 1) {
                float ov = __shfl_xor(bv, off);
                int oi = __shfl_xor(bi, off);
                if (ov > bv || (ov == bv && oi < bi)) { bv = ov; bi = oi; }
            }
            if (tid == 0) selrow[t] = bi;
            if (j == bi) v = -3e38f;
        }
    }

    f32x4 oacc[4];
#pragma unroll
    for (int dt = 0; dt < 4; ++dt) oacc[dt] = (f32x4){0.f, 0.f, 0.f, 0.f};
    char* Ps = U + 8192 + w * 2048;
    for (int ct = 0; ct < NCT; ++ct) {
        __syncthreads();
#pragma unroll
        for (int p = 0; p < 2; ++p) {
            int idx = tid + p * 256;
            int row = idx >> 3;           // d 0..63
            int c8 = idx & 7;
            size_t src = ((size_t)bh * HDd + row) * NCc + ct * 64 + c8 * 8;
            *(f16x8*)(U + swz(row, row * 128 + c8 * 16)) = *(const f16x8*)(vct + src);
        }
        {
            int r = l >> 2;
            int c0 = (l & 3) * 16;
            float ri = rinv[w * 16 + r];
            const float* pr = &Pm[(w * 16 + r) * 132 + ct * 64 + c0];
            float4 p0 = *(const float4*)(pr);
            float4 p1 = *(const float4*)(pr + 4);
            float4 p2 = *(const float4*)(pr + 8);
            float4 p3 = *(const float4*)(pr + 12);
            f16x8 h0, h1;
            h0[0] = (_Float16)(p0.x * ri); h0[1] = (_Float16)(p0.y * ri);
            h0[2] = (_Float16)(p0.z * ri); h0[3] = (_Float16)(p0.w * ri);
            h0[4] = (_Float16)(p1.x * ri); h0[5] = (_Float16)(p1.y * ri);
            h0[6] = (_Float16)(p1.z * ri); h0[7] = (_Float16)(p1.w * ri);
            h1[0] = (_Float16)(p2.x * ri); h1[1] = (_Float16)(p2.y * ri);
            h1[2] = (_Float16)(p2.z * ri); h1[3] = (_Float16)(p2.w * ri);
            h1[4] = (_Float16)(p3.x * ri); h1[5] = (_Float16)(p3.y * ri);
            h1[6] = (_Float16)(p3.z * ri); h1[7] = (_Float16)(p3.w * ri);
            *(f16x8*)(Ps + swz(r, r * 128 + c0 * 2)) = h0;
            *(f16x8*)(Ps + swz(r, r * 128 + c0 * 2 + 16)) = h1;
        }
        __syncthreads();
        f16x8 pa0 = *(const f16x8*)(Ps + swz(lr, lr * 128 + lg * 16));
        f16x8 pa1 = *(const f16x8*)(Ps + swz(lr, lr * 128 + lg * 16 + 64));
#pragma unroll
        for (int dt = 0; dt < 4; ++dt) {
            int vrow = dt * 16 + lr;
            f16x8 vb0 = *(const f16x8*)(U + swz(vrow, vrow * 128 + lg * 16));
            f16x8 vb1 = *(const f16x8*)(U + swz(vrow, vrow * 128 + lg * 16 + 64));
            oacc[dt] = __builtin_amdgcn_mfma_f32_16x16x32_f16(pa0, vb0, oacc[dt], 0, 0, 0);
            oacc[dt] = __builtin_amdgcn_mfma_f32_16x16x32_f16(pa1, vb1, oacc[dt], 0, 0, 0);
        }
    }

#pragma unroll
    for (int rg = 0; rg < 4; ++rg) {
        int row = w * 16 + 4 * lg + rg;
        int s = q0 + row;
        float g0 = g[((size_t)(b * Ss + s)) * 3 + 0];
#pragma unroll
        for (int dt = 0; dt < 4; ++dt)
            o[((size_t)(b * Ss + s)) * DMm + h * HDd + dt * 16 + lr] = g0 * oacc[dt][rg];
    }
}

// -------------------- K6: split MFMA attention (sel | win phases) -------------
// Softmax-lite sums are associative -> sel (16 tiles) and win (<=9 tiles) run
// as INDEPENDENT blocks (2048 total), each self-normalizing via ones-MFMA and
// atomicAdd-ing gated output into o. Halves each block's serial chain.
__global__ __launch_bounds__(256) void k_attn3(const f16* __restrict__ qh,
        const f16* __restrict__ kh, const f16* __restrict__ vt,
        const int* __restrict__ sel, const float* __restrict__ g,
        float* __restrict__ o)
{
    const int bid = blockIdx.x + 64 * blockIdx.y;   // 0..2047
    const int bh = ((bid & 7) << 1) | ((bid >> 3) & 1);
    const int phase = (bid >> 4) & 1;               // 0 = selected, 1 = window
    const int qb = bid >> 5;
    const int b = bh >> 3, h = bh & 7;
    const int q0 = qb * 64;
    const int tid = threadIdx.x;
    const int w  = tid >> 6;      // wave 0..3
    const int l  = tid & 63;
    const int lr = l & 15;
    const int lg = l >> 4;

    __shared__ __align__(16) char smem[32768];
    // K dbuf: [0,8K) [8K,16K); V dbuf: [16K,24K) [24K,32K)

    f16x8 qf0, qf1;
    {
        const f16* qptr = qh + ((size_t)bh * Ss + q0 + w * 16 + lr) * HDd + lg * 8;
        qf0 = *(const f16x8*)(qptr);
        qf1 = *(const f16x8*)(qptr + 32);
    }
    f16x8 kone;
#pragma unroll
    for (int j = 0; j < 8; ++j) kone[j] = (_Float16)1.f;

    const int W0 = (qb < 8) ? (8 - qb) : 0;
    const int NT = phase ? (9 - W0) : TOPKk;
    const int* selrow = sel + ((size_t)bh * NSs + qb) * TOPKk;
    const int kwb0 = qb - 8 + W0;      // first window block

    f32x4 oacc[4], oacc5;
#pragma unroll
    for (int dt = 0; dt < 4; ++dt) oacc[dt] = (f32x4){0.f, 0.f, 0.f, 0.f};
    oacc5 = (f32x4){0.f, 0.f, 0.f, 0.f};

    const int srow0 = tid >> 3, sc8 = tid & 7;
    const int srow1 = (tid + 256) >> 3;
    f16x8 pk0, pk1, pv0, pv1;

    // prologue: stage tile 0 into buf 0
    int kb_cur = phase ? kwb0 : __builtin_amdgcn_readfirstlane(selrow[0]);
    {
        size_t kbase = (size_t)bh * Ss + kb_cur * 64;
        pk0 = *(const f16x8*)(kh + (kbase + srow0) * HDd + sc8 * 8);
        pk1 = *(const f16x8*)(kh + (kbase + srow1) * HDd + sc8 * 8);
        pv0 = *(const f16x8*)(vt + ((size_t)bh * HDd + srow0) * Ss + kb_cur * 64 + sc8 * 8);
        pv1 = *(const f16x8*)(vt + ((size_t)bh * HDd + srow1) * Ss + kb_cur * 64 + sc8 * 8);
        *(f16x8*)(smem + swz(srow0, srow0 * 128 + sc8 * 16)) = pk0;
        *(f16x8*)(smem + swz(srow1, srow1 * 128 + sc8 * 16)) = pk1;
        STAGE_V(smem + 16384, pv0, srow0, sc8);
        STAGE_V(smem + 16384, pv1, srow1, sc8);
    }
    __syncthreads();

    int cur = 0;
    for (int t = 0; t < NT; ++t) {
        // ---- prefetch issue (next tile -> regs) -----------------------------
        int kb_nxt = 0;
        const bool hasNext = (t + 1 < NT);
        if (hasNext) {
            kb_nxt = phase ? (kwb0 + t + 1)
                           : __builtin_amdgcn_readfirstlane(selrow[t + 1]);
            size_t kbase = (size_t)bh * Ss + kb_nxt * 64;
            pk0 = *(const f16x8*)(kh + (kbase + srow0) * HDd + sc8 * 8);
            pk1 = *(const f16x8*)(kh + (kbase + srow1) * HDd + sc8 * 8);
            pv0 = *(const f16x8*)(vt + ((size_t)bh * HDd + srow0) * Ss + kb_nxt * 64 + sc8 * 8);
            pv1 = *(const f16x8*)(vt + ((size_t)bh * HDd + srow1) * Ss + kb_nxt * 64 + sc8 * 8);
        }
        const char* Kc = smem + (cur ? 8192 : 0);
        const char* Vc = smem + 16384 + (cur ? 8192 : 0);

        // ---- mask mode (block-uniform): 0 none, 1 causal, 2 anti; skip ------
        int mm = 0;
        bool skip = false;
        if (phase) {
            if (t == NT - 1) mm = 1;                   // kb == qb: diagonal causal
            else if (W0 == 0 && t == 0) mm = 2;        // kb == qb-8: anti j>r
        } else {
            if (t == 0) mm = 1;                        // selrow[0] == qb (own +1e9)
            else if (kb_cur > qb) skip = true;         // garbage sel (small qb)
        }

        if (!skip) {
            // ---- swapped QK^T + exp2 softmax-lite ---------------------------
            f16x8 pa8[2];
#pragma unroll
            for (int kt = 0; kt < 4; ++kt) {
                int krow = kt * 16 + lr;
                f16x8 kb0 = *(const f16x8*)(Kc + swz(krow, krow * 128 + lg * 16));
                f16x8 kb1 = *(const f16x8*)(Kc + swz(krow, krow * 128 + lg * 16 + 64));
                f32x4 c = (f32x4){0.f, 0.f, 0.f, 0.f};
                c = __builtin_amdgcn_mfma_f32_16x16x32_f16(kb0, qf0, c, 0, 0, 0);
                c = __builtin_amdgcn_mfma_f32_16x16x32_f16(kb1, qf1, c, 0, 0, 0);
#pragma unroll
                for (int rg = 0; rg < 4; ++rg) {
                    float sc = c[rg];
                    if (mm == 1) {
                        if (kt * 16 + 4 * lg + rg > w * 16 + lr) sc = NEGF;
                    } else if (mm == 2) {
                        if (kt * 16 + 4 * lg + rg <= w * 16 + lr) sc = NEGF;
                    }
                    float p = fexp2(sc);
                    pa8[kt >> 1][(kt & 1) * 4 + rg] = (_Float16)p;
                }
            }
            // row-sum denominators on the matrix pipe (rows match oacc's rows)
            oacc5 = __builtin_amdgcn_mfma_f32_16x16x32_f16(pa8[0], kone, oacc5, 0, 0, 0);
            oacc5 = __builtin_amdgcn_mfma_f32_16x16x32_f16(pa8[1], kone, oacc5, 0, 0, 0);

            // ---- PV: quad-interleaved V^T, b128 conflict-free ---------------
#pragma unroll
            for (int dt = 0; dt < 4; ++dt) {
                int vrow = dt * 16 + lr;
#pragma unroll
                for (int ktp = 0; ktp < 2; ++ktp) {
                    f16x8 vb = *(const f16x8*)(Vc + swz(vrow, vrow * 128 + ktp * 64 + lg * 16));
                    oacc[dt] = __builtin_amdgcn_mfma_f32_16x16x32_f16(pa8[ktp], vb, oacc[dt], 0, 0, 0);
                }
            }
        }

        // ---- write prefetched tile into the other buffer --------------------
        if (hasNext) {
            char* Kn = smem + (cur ? 0 : 8192);
            char* Vn = smem + 16384 + (cur ? 0 : 8192);
            *(f16x8*)(Kn + swz(srow0, srow0 * 128 + sc8 * 16)) = pk0;
            *(f16x8*)(Kn + swz(srow1, srow1 * 128 + sc8 * 16)) = pk1;
            STAGE_V(Vn, pv0, srow0, sc8);
            STAGE_V(Vn, pv1, srow1, sc8);
        }
        __syncthreads();
        cur ^= 1;
        kb_cur = kb_nxt;
    }

    // ---- epilogue: normalize, gate, atomicAdd into o ------------------------
    float* Os = (float*)smem;
#pragma unroll
    for (int rg = 0; rg < 4; ++rg) {
        float inv = 1.f / oacc5[rg];
        int row = w * 16 + 4 * lg + rg;
        int sq = q0 + row;
        float gv = g[((size_t)(b * Ss + sq)) * 3 + (phase ? 2 : 1)];
#pragma unroll
        for (int dt = 0; dt < 4; ++dt)
            Os[row * 68 + dt * 16 + lr] = gv * oacc[dt][rg] * inv;
    }
    __syncthreads();
    {
        int row = tid >> 2;
        int c0 = (tid & 3) * 16;
        int s = q0 + row;
        float* op = o + ((size_t)(b * Ss + s)) * DMm + h * HDd + c0;
#pragma unroll
        for (int j = 0; j < 16; ++j)
            atomicAdd(&op[j], Os[row * 68 + c0 + j]);
    }
}

// -------------------- constant emitter (host-side contract checks) ------------
__global__ __launch_bounds__(256) void k_const(float* __restrict__ y, float val)
{
    int i = blockIdx.x * 256 + threadIdx.x;
    y[i] = val;
}

// -------------------- launch --------------------------------------------------
extern "C" void kernel_launch(void* const* d_in, const int* in_sizes, int n_in,
                              void* d_out, int out_size, void* d_ws, size_t ws_size,
                              hipStream_t stream) {
    float* y = (float*)d_out;
    if (n_in != 6) {
        k_const<<<dim3(16384), 256, 0, stream>>>(y, 88888.f);
        return;
    }
    if (in_sizes[0] != 4194304 || in_sizes[1] != 262144 || in_sizes[2] != 262144 ||
        in_sizes[3] != 262144 || in_sizes[4] != 262144 || in_sizes[5] != 1536) {
        k_const<<<dim3(16384), 256, 0, stream>>>(y, 77777.f);
        return;
    }
    if (ws_size < WS_FLOATS * sizeof(float)) {
        k_const<<<dim3(16384), 256, 0, stream>>>(y, 66666.f);
        return;
    }

    const float* x  = (const float*)d_in[0];
    const float* Wq = (const float*)d_in[1];
    const float* Wk = (const float*)d_in[2];
    const float* Wv = (const float*)d_in[3];
    const float* Wo = (const float*)d_in[4];
    const float* Wg = (const float*)d_in[5];
    float* ws = (float*)d_ws;

    float* ow   = ws + OFF_O;
    float* gw   = ws + OFF_G;
    int*   selw = (int*)(ws + OFF_SEL);
    f16*   qhw  = (f16*)(ws + OFF_QH);
    f16*   qlw  = (f16*)(ws + OFF_QL);
    f16*   khw  = (f16*)(ws + OFF_KH);
    f16*   klw  = (f16*)(ws + OFF_KL);
    f16*   vtw  = (f16*)(ws + OFF_VT);
    f16*   kchw = (f16*)(ws + OFF_KCH);
    f16*   kclw = (f16*)(ws + OFF_KCL);
    f16*   vctw = (f16*)(ws + OFF_VCT);
    f16*   xhw  = (f16*)(ws + OFF_XH);   // aliases o region (freed before k_cmp)
    f16*   xlw  = (f16*)(ws + OFF_XL);
    f16*   wqh  = (f16*)(ws + OFF_WT);
    f16*   wql  = (f16*)(ws + OFF_WT + 131072);
    f16*   wkh  = (f16*)(ws + OFF_WT + 262144);
    f16*   wkl  = (f16*)(ws + OFF_WT + 393216);
    f16*   wvh  = (f16*)(ws + OFF_WT + 524288);
    f16*   wvl  = (f16*)(ws + OFF_WT + 655360);
    f16*   woh  = (f16*)(ws + OFF_WT + 786432);

    k_prep_xg<<<dim3(2048), 256, 0, stream>>>(x, Wg, xhw, xlw, gw);
    k_prep_w<<<dim3(8, 8, 4), 256, 0, stream>>>(Wq, Wk, Wv, Wo,
            wqh, wql, wkh, wkl, wvh, wvl, woh);
    k_gemm3<<<dim3(64, 8, 3), 256, 0, stream>>>(xhw, xlw,
            wqh, wql, wkh, wkl, wvh, qhw, qlw, khw, klw, vtw);
    k_pool<<<dim3(512), 256, 0, stream>>>(khw, klw, vtw, kchw, kclw, vctw);
    k_cmp<<<dim3(64, 16), 256, 0, stream>>>(qhw, qlw, kchw, kclw, vctw, gw, selw, ow);
    k_attn3<<<dim3(64, 32), 256, 0, stream>>>(qhw, khw, vtw, selw, gw, ow);
    k_outproj<<<dim3(64, 8), 256, 0, stream>>>(ow, woh, y);
}

// Round 12
// 253.414 us; speedup vs baseline: 2.3188x; 2.3188x over previous
//
#include <hip/hip_runtime.h>

// Problem constants
#define Hh    8
#define DMm   512
#define HDd   64
#define CBc   32
#define SBs   64
#define WINSZ 512
#define TOPKk 16
#define NEGF  (-1e30f)
#define Bb    2
#define Ss    4096
#define NCc   128   // S/CB
#define NSs   64    // S/SB
#define SCALE 0.125f
#define PSC   0.18033688011112042f   // SCALE * log2(e): q pre-scale -> exp2 softmax

// Workspace layout (float offsets)
#define OFF_KL   ((size_t)4194304)    // f16 k_lo [bh][s][d]
#define OFF_O    ((size_t)12582912)   // ALIASED: x_hi/x_lo live here until k_cmp writes o
#define OFF_G    ((size_t)16777216)   // B*S*3 = 24576
#define OFF_KC   ((size_t)16801792)   // kc_hi/kc_lo f16 (2 x 131072 halves)
#define OFF_VC   ((size_t)16932864)   // vc^T f16 (131072 halves)
#define OFF_IMPB ((size_t)17063936)   // (unused; kept for layout stability)
#define OFF_SEL  ((size_t)17129472)   // B*H*NS*TOPK ints = 16384
#define OFF_QH   ((size_t)17145856)   // f16 q  [bh][s][d] (pre-scaled by PSC)
#define OFF_KH   ((size_t)19243008)   // f16 k_hi [bh][s][d]
#define OFF_VT   ((size_t)21340160)   // f16 v^T [bh][d][s]
#define OFF_WT   ((size_t)23437312)   // 7 x 131072 floats of f16 W^T (hi/lo)
#define OFF_QL   ((size_t)24354816)   // f16 q_lo [bh][s][d] (pre-scaled by PSC)
#define WS_FLOATS ((size_t)25403392)

// x_hi/x_lo alias the o region (o first written by k_cmp, after GEMMs)
#define OFF_XH   (OFF_O)
#define OFF_XL   (OFF_O + 2097152)

#define OFF_KCH  (OFF_KC)
#define OFF_KCL  (OFF_KC + 65536)
#define OFF_VCT  (OFF_VC)

typedef _Float16 f16;
typedef _Float16 f16x4 __attribute__((ext_vector_type(4)));
typedef _Float16 f16x8 __attribute__((ext_vector_type(8)));
typedef float    f32x4 __attribute__((ext_vector_type(4)));

__device__ __forceinline__ int swz(int row, int byteoff) {
    return byteoff ^ ((row & 7) << 4);   // spreads stride-128B rows across banks
}
__device__ __forceinline__ float fexp2(float x) {
    return __builtin_amdgcn_exp2f(x);    // v_exp_f32: D = 2^S0
}

// V LDS layout: per 32-key block, quads interleaved as {4lg, 16+4lg} so that a
// single b128 read at [ktp*64 + lg*16] yields keys {ktp*32+4lg+0..3, +16+0..3}
// (matches in-register P order for mfma_16x16x32). Write side: 2 x b64.
#define STAGE_V(Vbase, vd, row, c8) do {                                     \
    int q0_ = ((c8) & 3) * 2, q1_ = q0_ + 1;                                 \
    int col0_ = ((c8) >> 2) * 64 + (q0_ & 3) * 16 + (q0_ >> 2) * 8;          \
    int col1_ = ((c8) >> 2) * 64 + (q1_ & 3) * 16 + (q1_ >> 2) * 8;          \
    f16x4 lo_ = { (vd)[0], (vd)[1], (vd)[2], (vd)[3] };                      \
    f16x4 hi_ = { (vd)[4], (vd)[5], (vd)[6], (vd)[7] };                      \
    *(f16x4*)((Vbase) + swz(row, (row) * 128 + col0_)) = lo_;                \
    *(f16x4*)((Vbase) + swz(row, (row) * 128 + col1_)) = hi_;                \
} while (0)

// -------------------- K0a: fused x -> x_hi/x_lo + gate ------------------------
__global__ __launch_bounds__(256) void k_prep_xg(const float* __restrict__ x,
        const float* __restrict__ Wg, f16* __restrict__ xh, f16* __restrict__ xl,
        float* __restrict__ g)
{
    const int w = threadIdx.x >> 6, l = threadIdx.x & 63;
    const int row = blockIdx.x * 4 + w;        // 0..8191
    const int d0 = l * 8;
    const float* xr = x + (size_t)row * DMm + d0;
    float4 a = *(const float4*)(xr);
    float4 b = *(const float4*)(xr + 4);
    float xv[8] = { a.x, a.y, a.z, a.w, b.x, b.y, b.z, b.w };
    f16x8 h, lo;
#pragma unroll
    for (int j = 0; j < 8; ++j) {
        h[j] = (_Float16)xv[j];
        lo[j] = (_Float16)(xv[j] - (float)h[j]);
    }
    size_t base = (size_t)row * DMm + d0;
    *(f16x8*)(xh + base) = h;
    *(f16x8*)(xl + base) = lo;
    float s0 = 0.f, s1 = 0.f, s2 = 0.f;
#pragma unroll
    for (int j = 0; j < 8; ++j) {
        const float* wr = Wg + (size_t)(d0 + j) * 3;
        s0 += xv[j] * wr[0];
        s1 += xv[j] * wr[1];
        s2 += xv[j] * wr[2];
    }
#pragma unroll
    for (int off = 1; off < 64; off <<= 1) {
        s0 += __shfl_xor(s0, off);
        s1 += __shfl_xor(s1, off);
        s2 += __shfl_xor(s2, off);
    }
    if (l == 0) {
        g[(size_t)row * 3 + 0] = 1.f / (1.f + expf(-s0));
        g[(size_t)row * 3 + 1] = 1.f / (1.f + expf(-s1));
        g[(size_t)row * 3 + 2] = 1.f / (1.f + expf(-s2));
    }
}

// -------------------- K0b: W -> W^T hi/lo (f16) -------------------------------
__global__ __launch_bounds__(256) void k_prep_w(
        const float* __restrict__ Wq, const float* __restrict__ Wk,
        const float* __restrict__ Wv, const float* __restrict__ Wo,
        f16* __restrict__ wqh, f16* __restrict__ wql,
        f16* __restrict__ wkh, f16* __restrict__ wkl,
        f16* __restrict__ wvh, f16* __restrict__ wvl,
        f16* __restrict__ woh)
{
    const int k0 = blockIdx.x * 64;
    const int n0 = blockIdx.y * 64;
    const int z = blockIdx.z;
    const float* W = (z == 0) ? Wq : ((z == 1) ? Wk : ((z == 2) ? Wv : Wo));
    f16* dh = (z == 0) ? wqh : ((z == 1) ? wkh : ((z == 2) ? wvh : woh));
    f16* dl = (z == 0) ? wql : ((z == 1) ? wkl : ((z == 2) ? wvl : (f16*)0));
    __shared__ float T[64][68];
    const int tid = threadIdx.x;
    {
        int r = tid >> 2;
        int c16 = (tid & 3) * 16;
#pragma unroll
        for (int j = 0; j < 4; ++j) {
            float4 w4 = *(const float4*)(W + (size_t)(k0 + r) * DMm + n0 + c16 + j * 4);
            *(float4*)&T[r][c16 + j * 4] = w4;
        }
    }
    __syncthreads();
    {
        int n = tid >> 2;
        int k16 = (tid & 3) * 16;
        f16x8 h0, h1, l0, l1;
#pragma unroll
        for (int j = 0; j < 8; ++j) {
            float wv = T[k16 + j][n];
            h0[j] = (_Float16)wv; l0[j] = (_Float16)(wv - (float)h0[j]);
        }
#pragma unroll
        for (int j = 0; j < 8; ++j) {
            float wv = T[k16 + 8 + j][n];
            h1[j] = (_Float16)wv; l1[j] = (_Float16)(wv - (float)h1[j]);
        }
        size_t o = (size_t)(n0 + n) * DMm + k0 + k16;
        *(f16x8*)(dh + o) = h0;
        *(f16x8*)(dh + o + 8) = h1;
        if (dl) { *(f16x8*)(dl + o) = l0; *(f16x8*)(dl + o + 8) = l1; }
    }
}

// -------------------- K1: merged q/k/v projection GEMMs -----------------------
__global__ __launch_bounds__(256) void k_gemm3(
        const f16* __restrict__ xh, const f16* __restrict__ xl,
        const f16* __restrict__ wqh, const f16* __restrict__ wql,
        const f16* __restrict__ wkh, const f16* __restrict__ wkl,
        const f16* __restrict__ wvh,
        f16* __restrict__ qh, f16* __restrict__ ql,
        f16* __restrict__ kh, f16* __restrict__ kl,
        f16* __restrict__ vt)
{
    const int z = blockIdx.z;
    const int m0 = blockIdx.x * 128;
    const int n0 = blockIdx.y * 64;
    const int tid = threadIdx.x;
    const int w = tid >> 6, l = tid & 63;
    const int lr = l & 15, lg = l >> 4;
    const int wm = w >> 1, wn = w & 1;

    __shared__ f16 As[2][128 * 40];
    __shared__ f16 Bs[2][64 * 40];

    f32x4 acc[4][2];
#pragma unroll
    for (int mf = 0; mf < 4; ++mf)
#pragma unroll
        for (int nf = 0; nf < 2; ++nf) acc[mf][nf] = (f32x4){0.f, 0.f, 0.f, 0.f};

    const int ar = tid >> 1, ac = (tid & 1) * 16;
    const int bn = tid >> 2, bc = (tid & 3) * 8;

    if (z == 2) {
        // ---- v path: plain f16, swapped-operand MFMA -> transposed out ------
        for (int k0 = 0; k0 < DMm; k0 += 32) {
            {
                const f16* src = xh + (size_t)(m0 + ar) * DMm + k0 + ac;
                *(f16x8*)&As[0][ar * 40 + ac] = *(const f16x8*)src;
                *(f16x8*)&As[0][ar * 40 + ac + 8] = *(const f16x8*)(src + 8);
                const f16* srcb = wvh + (size_t)(n0 + bn) * DMm + k0 + bc;
                *(f16x8*)&Bs[0][bn * 40 + bc] = *(const f16x8*)srcb;
            }
            __syncthreads();
            f16x8 ahf[4], bhf[2];
#pragma unroll
            for (int mf = 0; mf < 4; ++mf)
                ahf[mf] = *(const f16x8*)&As[0][(wm * 64 + mf * 16 + lr) * 40 + lg * 8];
#pragma unroll
            for (int nf = 0; nf < 2; ++nf)
                bhf[nf] = *(const f16x8*)&Bs[0][(wn * 32 + nf * 16 + lr) * 40 + lg * 8];
#pragma unroll
            for (int mf = 0; mf < 4; ++mf)
#pragma unroll
                for (int nf = 0; nf < 2; ++nf)
                    acc[mf][nf] = __builtin_amdgcn_mfma_f32_16x16x32_f16(bhf[nf], ahf[mf], acc[mf][nf], 0, 0, 0);
            __syncthreads();
        }
        const int h = n0 >> 6;
#pragma unroll
        for (int mf = 0; mf < 4; ++mf)
#pragma unroll
            for (int nf = 0; nf < 2; ++nf)
#pragma unroll
                for (int rg = 0; rg < 4; ++rg) {
                    int n = n0 + wn * 32 + nf * 16 + 4 * lg + rg;   // d (global)
                    int m = m0 + wm * 64 + mf * 16 + lr;            // s (incl batch)
                    int b = m >> 12, s = m & 4095;
                    vt[(((size_t)(b * Hh + h)) * HDd + (n & 63)) * Ss + s] =
                        (f16)acc[mf][nf][rg];
                }
        return;
    }

    // ---- q/k path: split-f16 (3-product, fp32-grade) ------------------------
    const f16* Bh = z ? wkh : wqh;
    const f16* Bl = z ? wkl : wql;
    f16* Ch = z ? kh : qh;
    f16* Cl = z ? kl : ql;
    const float cscale = z ? 1.f : PSC;

    for (int k0 = 0; k0 < DMm; k0 += 32) {
        {
            const f16* src = xh + (size_t)(m0 + ar) * DMm + k0 + ac;
            *(f16x8*)&As[0][ar * 40 + ac] = *(const f16x8*)src;
            *(f16x8*)&As[0][ar * 40 + ac + 8] = *(const f16x8*)(src + 8);
            const f16* src2 = xl + (size_t)(m0 + ar) * DMm + k0 + ac;
            *(f16x8*)&As[1][ar * 40 + ac] = *(const f16x8*)src2;
            *(f16x8*)&As[1][ar * 40 + ac + 8] = *(const f16x8*)(src2 + 8);
        }
        {
            const f16* src = Bh + (size_t)(n0 + bn) * DMm + k0 + bc;
            *(f16x8*)&Bs[0][bn * 40 + bc] = *(const f16x8*)src;
            const f16* src2 = Bl + (size_t)(n0 + bn) * DMm + k0 + bc;
            *(f16x8*)&Bs[1][bn * 40 + bc] = *(const f16x8*)src2;
        }
        __syncthreads();

        f16x8 ahf[4], alf[4], bhf[2], blf[2];
#pragma unroll
        for (int mf = 0; mf < 4; ++mf) {
            int row = wm * 64 + mf * 16 + lr;
            ahf[mf] = *(const f16x8*)&As[0][row * 40 + lg * 8];
            alf[mf] = *(const f16x8*)&As[1][row * 40 + lg * 8];
        }
#pragma unroll
        for (int nf = 0; nf < 2; ++nf) {
            int row = wn * 32 + nf * 16 + lr;
            bhf[nf] = *(const f16x8*)&Bs[0][row * 40 + lg * 8];
            blf[nf] = *(const f16x8*)&Bs[1][row * 40 + lg * 8];
        }
#pragma unroll
        for (int mf = 0; mf < 4; ++mf)
#pragma unroll
            for (int nf = 0; nf < 2; ++nf) {
                acc[mf][nf] = __builtin_amdgcn_mfma_f32_16x16x32_f16(ahf[mf], bhf[nf], acc[mf][nf], 0, 0, 0);
                acc[mf][nf] = __builtin_amdgcn_mfma_f32_16x16x32_f16(ahf[mf], blf[nf], acc[mf][nf], 0, 0, 0);
                acc[mf][nf] = __builtin_amdgcn_mfma_f32_16x16x32_f16(alf[mf], bhf[nf], acc[mf][nf], 0, 0, 0);
            }
        __syncthreads();
    }

#pragma unroll
    for (int mf = 0; mf < 4; ++mf)
#pragma unroll
        for (int nf = 0; nf < 2; ++nf)
#pragma unroll
            for (int rg = 0; rg < 4; ++rg) {
                int m = m0 + wm * 64 + mf * 16 + 4 * lg + rg;
                int n = n0 + wn * 32 + nf * 16 + lr;
                int b = m >> 12, s = m & 4095;
                int h = n >> 6, d = n & 63;
                size_t o = (((size_t)(b * Hh + h)) * Ss + s) * HDd + d;
                float vs = acc[mf][nf][rg] * cscale;
                f16 hv = (f16)vs;
                Ch[o] = hv;
                Cl[o] = (f16)(vs - (float)hv);
            }
}

// -------------------- K1c: outproj GEMM (fp32 A staged, plain f16) ------------
__global__ __launch_bounds__(256) void k_outproj(const float* __restrict__ Af,
        const f16* __restrict__ Bh, float* __restrict__ Cf)
{
    const int m0 = blockIdx.x * 128;
    const int n0 = blockIdx.y * 64;
    const int tid = threadIdx.x;
    const int w = tid >> 6, l = tid & 63;
    const int lr = l & 15, lg = l >> 4;
    const int wm = w >> 1, wn = w & 1;

    __shared__ f16 As[128 * 40];
    __shared__ f16 Bs[64 * 40];

    f32x4 acc[4][2];
#pragma unroll
    for (int mf = 0; mf < 4; ++mf)
#pragma unroll
        for (int nf = 0; nf < 2; ++nf) acc[mf][nf] = (f32x4){0.f, 0.f, 0.f, 0.f};

    const int ar = tid >> 1, ac = (tid & 1) * 16;
    const int bn = tid >> 2, bc = (tid & 3) * 8;

    for (int k0 = 0; k0 < DMm; k0 += 32) {
        {
            const float* src = Af + (size_t)(m0 + ar) * DMm + k0 + ac;
            float4 a0 = *(const float4*)(src);
            float4 a1 = *(const float4*)(src + 4);
            float4 a2 = *(const float4*)(src + 8);
            float4 a3 = *(const float4*)(src + 12);
            f16x8 h0, h1;
            h0[0] = (_Float16)a0.x; h0[1] = (_Float16)a0.y; h0[2] = (_Float16)a0.z; h0[3] = (_Float16)a0.w;
            h0[4] = (_Float16)a1.x; h0[5] = (_Float16)a1.y; h0[6] = (_Float16)a1.z; h0[7] = (_Float16)a1.w;
            h1[0] = (_Float16)a2.x; h1[1] = (_Float16)a2.y; h1[2] = (_Float16)a2.z; h1[3] = (_Float16)a2.w;
            h1[4] = (_Float16)a3.x; h1[5] = (_Float16)a3.y; h1[6] = (_Float16)a3.z; h1[7] = (_Float16)a3.w;
            *(f16x8*)&As[ar * 40 + ac] = h0;
            *(f16x8*)&As[ar * 40 + ac + 8] = h1;
            const f16* srcb = Bh + (size_t)(n0 + bn) * DMm + k0 + bc;
            *(f16x8*)&Bs[bn * 40 + bc] = *(const f16x8*)srcb;
        }
        __syncthreads();
        f16x8 ahf[4], bhf[2];
#pragma unroll
        for (int mf = 0; mf < 4; ++mf)
            ahf[mf] = *(const f16x8*)&As[(wm * 64 + mf * 16 + lr) * 40 + lg * 8];
#pragma unroll
        for (int nf = 0; nf < 2; ++nf)
            bhf[nf] = *(const f16x8*)&Bs[(wn * 32 + nf * 16 + lr) * 40 + lg * 8];
#pragma unroll
        for (int mf = 0; mf < 4; ++mf)
#pragma unroll
            for (int nf = 0; nf < 2; ++nf)
                acc[mf][nf] = __builtin_amdgcn_mfma_f32_16x16x32_f16(ahf[mf], bhf[nf], acc[mf][nf], 0, 0, 0);
        __syncthreads();
    }
#pragma unroll
    for (int mf = 0; mf < 4; ++mf)
#pragma unroll
        for (int nf = 0; nf < 2; ++nf)
#pragma unroll
            for (int rg = 0; rg < 4; ++rg) {
                int m = m0 + wm * 64 + mf * 16 + 4 * lg + rg;
                int n = n0 + wn * 32 + nf * 16 + lr;
                Cf[(size_t)m * DMm + n] = acc[mf][nf][rg];
            }
}

// -------------------- K3: mean-pool from f16 k_hi/k_lo and vt -----------------
__global__ __launch_bounds__(256) void k_pool(const f16* __restrict__ kh,
        const f16* __restrict__ kl, const f16* __restrict__ vt,
        f16* __restrict__ kch, f16* __restrict__ kcl, f16* __restrict__ vct)
{
    int idx = blockIdx.x * 256 + threadIdx.x;  // B*H*NC*HD = 131072
    int bh = idx >> 13;
    {
        int d = idx & 63;
        int n = (idx >> 6) & 127;
        const f16* kp = kh + ((size_t)bh * Ss + n * CBc) * HDd + d;
        const f16* lp = kl + ((size_t)bh * Ss + n * CBc) * HDd + d;
        float sk = 0.f;
        for (int t = 0; t < CBc; ++t)
            sk += (float)kp[(size_t)t * HDd] + (float)lp[(size_t)t * HDd];
        float mk = sk * (1.f / CBc);
        f16 h = (f16)mk;
        kch[idx] = h;
        kcl[idx] = (f16)(mk - (float)h);
    }
    {
        int vd = (idx >> 7) & 63;
        int vn = idx & 127;
        const f16* vp = vt + ((size_t)bh * HDd + vd) * Ss + vn * CBc;
        float sv = 0.f;
#pragma unroll
        for (int j = 0; j < 4; ++j) {
            f16x8 v8 = *(const f16x8*)(vp + j * 8);
#pragma unroll
            for (int e = 0; e < 8; ++e) sv += (float)v8[e];
        }
        vct[((size_t)bh * HDd + vd) * NCc + vn] = (f16)(sv * (1.f / CBc));
    }
}

// -------------------- K4: compressed attention + importance + FUSED top-k -----
__global__ __launch_bounds__(256) void k_cmp(const f16* __restrict__ qh,
        const f16* __restrict__ ql, const f16* __restrict__ kch,
        const f16* __restrict__ kcl, const f16* __restrict__ vct,
        const float* __restrict__ g, int* __restrict__ sel, float* __restrict__ o)
{
    const int qb = blockIdx.x;   // 0..63
    const int bh = blockIdx.y;   // 0..15
    const int b = bh >> 3, h = bh & 7;
    const int q0 = qb * 64;
    const int tid = threadIdx.x;
    const int w = tid >> 6, l = tid & 63;
    const int lr = l & 15, lg = l >> 4;

    __shared__ __align__(16) char smem[51456];
    float* Pm = (float*)smem;                       // [64][132] fp32 exp2 values
    char* U = smem + 33792;                         // 16KB union: {KCh,KCl} / {VCt,Ps}
    float* red2 = (float*)(smem + 33792 + 16384);   // 256 floats
    float* rinv = (float*)(smem + 51200);           // 64 floats

    const int NCT = (qb <= 30) ? 1 : 2;
    const int ncols = NCT * 64;

    f16x8 qfh0, qfh1, qfl0, qfl1;
    {
        size_t qoff = ((size_t)bh * Ss + q0 + w * 16 + lr) * HDd + lg * 8;
        qfh0 = *(const f16x8*)(qh + qoff);
        qfh1 = *(const f16x8*)(qh + qoff + 32);
        qfl0 = *(const f16x8*)(ql + qoff);
        qfl1 = *(const f16x8*)(ql + qoff + 32);
    }

    for (int ct = 0; ct < NCT; ++ct) {
        __syncthreads();
#pragma unroll
        for (int p = 0; p < 2; ++p) {
            int idx = tid + p * 256;
            int row = idx >> 3;           // chunk 0..63
            int c8 = idx & 7;
            size_t src = ((size_t)bh * NCc + ct * 64 + row) * HDd + c8 * 8;
            *(f16x8*)(U + swz(row, row * 128 + c8 * 16)) = *(const f16x8*)(kch + src);
            *(f16x8*)(U + 8192 + swz(row, row * 128 + c8 * 16)) = *(const f16x8*)(kcl + src);
        }
        __syncthreads();
#pragma unroll
        for (int kt = 0; kt < 4; ++kt) {
            int krow = kt * 16 + lr;
            f16x8 bh0 = *(const f16x8*)(U + swz(krow, krow * 128 + lg * 16));
            f16x8 bh1 = *(const f16x8*)(U + swz(krow, krow * 128 + lg * 16 + 64));
            f16x8 bl0 = *(const f16x8*)(U + 8192 + swz(krow, krow * 128 + lg * 16));
            f16x8 bl1 = *(const f16x8*)(U + 8192 + swz(krow, krow * 128 + lg * 16 + 64));
            f32x4 c = (f32x4){0.f, 0.f, 0.f, 0.f};
            c = __builtin_amdgcn_mfma_f32_16x16x32_f16(qfh0, bh0, c, 0, 0, 0);
            c = __builtin_amdgcn_mfma_f32_16x16x32_f16(qfh1, bh1, c, 0, 0, 0);
            c = __builtin_amdgcn_mfma_f32_16x16x32_f16(qfh0, bl0, c, 0, 0, 0);
            c = __builtin_amdgcn_mfma_f32_16x16x32_f16(qfh1, bl1, c, 0, 0, 0);
            c = __builtin_amdgcn_mfma_f32_16x16x32_f16(qfl0, bh0, c, 0, 0, 0);
            c = __builtin_amdgcn_mfma_f32_16x16x32_f16(qfl1, bh1, c, 0, 0, 0);
            int n = ct * 64 + kt * 16 + lr;
#pragma unroll
            for (int rg = 0; rg < 4; ++rg) {
                int row = w * 16 + 4 * lg + rg;
                int s = q0 + row;
                bool valid = (32 * n + 31 <= s);
                Pm[row * 132 + n] = valid ? c[rg] : NEGF;   // log2-domain score
            }
        }
    }
    __syncthreads();

    {
        int r = tid >> 2;
        int l4 = tid & 3;
        float m = NEGF;
        for (int c = l4; c < ncols; c += 4) m = fmaxf(m, Pm[r * 132 + c]);
        m = fmaxf(m, __shfl_xor(m, 1));
        m = fmaxf(m, __shfl_xor(m, 2));
        float sum = 0.f;
        if (m > NEGF * 0.5f) {
            for (int c = l4; c < ncols; c += 4) {
                float sv = Pm[r * 132 + c];
                float p = (sv <= NEGF * 0.5f) ? 0.f : fexp2(sv - m);
                Pm[r * 132 + c] = p;    // unnormalized
                sum += p;
            }
        } else {
            for (int c = l4; c < ncols; c += 4) Pm[r * 132 + c] = 0.f;
        }
        sum += __shfl_xor(sum, 1);
        sum += __shfl_xor(sum, 2);
        if (l4 == 0) rinv[r] = (sum > 0.f) ? 1.f / sum : 0.f;
    }
    __syncthreads();

    {
        float part = 0.f;
#pragma unroll
        for (int rr = 0; rr < 16; ++rr) {
            int qq = w * 16 + rr;
            int c = 2 * l;
            if (c < ncols) {
                float2 pv2 = *(const float2*)&Pm[qq * 132 + c];
                part += (pv2.x + pv2.y) * rinv[qq];
            }
        }
        red2[w * 64 + l] = part;
    }
    __syncthreads();
    if (tid < 64) {
        float tot = red2[tid] + red2[64 + tid] + red2[128 + tid] + red2[192 + tid];
        // fused top-k (wave 0): identical values + tie-break as old k_topk
        int j = tid;
        float v = tot;
        if (j > qb) v = NEGF;
        if (j == qb) v += 1e9f;
        int* selrow = sel + ((size_t)bh * NSs + qb) * TOPKk;
        for (int t = 0; t < TOPKk; ++t) {
            float bv = v; int bi = j;
#pragma unroll
            for (int off = 1; off < 64; off <<= 1) {
                float ov = __shfl_xor(bv, off);
                int oi = __shfl_xor(bi, off);
                if (ov > bv || (ov == bv && oi < bi)) { bv = ov; bi = oi; }
            }
            if (tid == 0) selrow[t] = bi;
            if (j == bi) v = -3e38f;
        }
    }

    f32x4 oacc[4];
#pragma unroll
    for (int dt = 0; dt < 4; ++dt) oacc[dt] = (f32x4){0.f, 0.f, 0.f, 0.f};
    char* Ps = U + 8192 + w * 2048;
    for (int ct = 0; ct < NCT; ++ct) {
        __syncthreads();
#pragma unroll
        for (int p = 0; p < 2; ++p) {
            int idx = tid + p * 256;
            int row = idx >> 3;           // d 0..63
            int c8 = idx & 7;
            size_t src = ((size_t)bh * HDd + row) * NCc + ct * 64 + c8 * 8;
            *(f16x8*)(U + swz(row, row * 128 + c8 * 16)) = *(const f16x8*)(vct + src);
        }
        {
            int r = l >> 2;
            int c0 = (l & 3) * 16;
            float ri = rinv[w * 16 + r];
            const float* pr = &Pm[(w * 16 + r) * 132 + ct * 64 + c0];
            float4 p0 = *(const float4*)(pr);
            float4 p1 = *(const float4*)(pr + 4);
            float4 p2 = *(const float4*)(pr + 8);
            float4 p3 = *(const float4*)(pr + 12);
            f16x8 h0, h1;
            h0[0] = (_Float16)(p0.x * ri); h0[1] = (_Float16)(p0.y * ri);
            h0[2] = (_Float16)(p0.z * ri); h0[3] = (_Float16)(p0.w * ri);
            h0[4] = (_Float16)(p1.x * ri); h0[5] = (_Float16)(p1.y * ri);
            h0[6] = (_Float16)(p1.z * ri); h0[7] = (_Float16)(p1.w * ri);
            h1[0] = (_Float16)(p2.x * ri); h1[1] = (_Float16)(p2.y * ri);
            h1[2] = (_Float16)(p2.z * ri); h1[3] = (_Float16)(p2.w * ri);
            h1[4] = (_Float16)(p3.x * ri); h1[5] = (_Float16)(p3.y * ri);
            h1[6] = (_Float16)(p3.z * ri); h1[7] = (_Float16)(p3.w * ri);
            *(f16x8*)(Ps + swz(r, r * 128 + c0 * 2)) = h0;
            *(f16x8*)(Ps + swz(r, r * 128 + c0 * 2 + 16)) = h1;
        }
        __syncthreads();
        f16x8 pa0 = *(const f16x8*)(Ps + swz(lr, lr * 128 + lg * 16));
        f16x8 pa1 = *(const f16x8*)(Ps + swz(lr, lr * 128 + lg * 16 + 64));
#pragma unroll
        for (int dt = 0; dt < 4; ++dt) {
            int vrow = dt * 16 + lr;
            f16x8 vb0 = *(const f16x8*)(U + swz(vrow, vrow * 128 + lg * 16));
            f16x8 vb1 = *(const f16x8*)(U + swz(vrow, vrow * 128 + lg * 16 + 64));
            oacc[dt] = __builtin_amdgcn_mfma_f32_16x16x32_f16(pa0, vb0, oacc[dt], 0, 0, 0);
            oacc[dt] = __builtin_amdgcn_mfma_f32_16x16x32_f16(pa1, vb1, oacc[dt], 0, 0, 0);
        }
    }

#pragma unroll
    for (int rg = 0; rg < 4; ++rg) {
        int row = w * 16 + 4 * lg + rg;
        int s = q0 + row;
        float g0 = g[((size_t)(b * Ss + s)) * 3 + 0];
#pragma unroll
        for (int dt = 0; dt < 4; ++dt)
            o[((size_t)(b * Ss + s)) * DMm + h * HDd + dt * 16 + lr] = g0 * oacc[dt][rg];
    }
}

// -------------------- K6: merged MFMA attention (selected + window) -----------
// Round-10 verified structure: single block owns both phases; ones-MFMA
// denominators; mask specialization; one plain-store RMW epilogue (NO atomics).
__global__ __launch_bounds__(256) void k_attn2(const f16* __restrict__ qh,
        const f16* __restrict__ kh, const f16* __restrict__ vt,
        const int* __restrict__ sel, const float* __restrict__ g,
        float* __restrict__ o)
{
    const int bid = blockIdx.x + 64 * blockIdx.y;   // 0..1023
    const int bh = ((bid & 7) << 1) | ((bid >> 3) & 1);
    const int qb = bid >> 4;
    const int b = bh >> 3, h = bh & 7;
    const int q0 = qb * 64;
    const int tid = threadIdx.x;
    const int w  = tid >> 6;      // wave 0..3
    const int l  = tid & 63;
    const int lr = l & 15;
    const int lg = l >> 4;

    __shared__ __align__(16) char smem[32768];
    // K dbuf: [0,8K) [8K,16K); V dbuf: [16K,24K) [24K,32K)

    f16x8 qf0, qf1;
    {
        const f16* qptr = qh + ((size_t)bh * Ss + q0 + w * 16 + lr) * HDd + lg * 8;
        qf0 = *(const f16x8*)(qptr);
        qf1 = *(const f16x8*)(qptr + 32);
    }
    f16x8 kone;
#pragma unroll
    for (int j = 0; j < 8; ++j) kone[j] = (_Float16)1.f;

    const int W0 = (qb < 8) ? (8 - qb) : 0;
    const int NT = 25 - W0;             // 16 selected + (9-W0) window
    const int* selrow = sel + ((size_t)bh * NSs + qb) * TOPKk;

    f32x4 oacc[4], osel[4], oacc5;
#pragma unroll
    for (int dt = 0; dt < 4; ++dt) {
        oacc[dt] = (f32x4){0.f, 0.f, 0.f, 0.f};
        osel[dt] = (f32x4){0.f, 0.f, 0.f, 0.f};
    }
    oacc5 = (f32x4){0.f, 0.f, 0.f, 0.f};

    const int srow0 = tid >> 3, sc8 = tid & 7;
    const int srow1 = (tid + 256) >> 3;
    f16x8 pk0, pk1, pv0, pv1;

    // prologue: stage tile 0 into buf 0
    int kb_cur = __builtin_amdgcn_readfirstlane(selrow[0]);
    {
        size_t kbase = (size_t)bh * Ss + kb_cur * 64;
        pk0 = *(const f16x8*)(kh + (kbase + srow0) * HDd + sc8 * 8);
        pk1 = *(const f16x8*)(kh + (kbase + srow1) * HDd + sc8 * 8);
        pv0 = *(const f16x8*)(vt + ((size_t)bh * HDd + srow0) * Ss + kb_cur * 64 + sc8 * 8);
        pv1 = *(const f16x8*)(vt + ((size_t)bh * HDd + srow1) * Ss + kb_cur * 64 + sc8 * 8);
        *(f16x8*)(smem + swz(srow0, srow0 * 128 + sc8 * 16)) = pk0;
        *(f16x8*)(smem + swz(srow1, srow1 * 128 + sc8 * 16)) = pk1;
        STAGE_V(smem + 16384, pv0, srow0, sc8);
        STAGE_V(smem + 16384, pv1, srow1, sc8);
    }
    __syncthreads();

    int cur = 0;
    for (int t = 0; t < NT; ++t) {
        // ---- prefetch issue (next tile -> regs) -----------------------------
        int kb_nxt = 0;
        const bool hasNext = (t + 1 < NT);
        if (hasNext) {
            kb_nxt = (t + 1 < 16) ? __builtin_amdgcn_readfirstlane(selrow[t + 1])
                                  : (qb - 8 + W0 + (t + 1 - 16));
            size_t kbase = (size_t)bh * Ss + kb_nxt * 64;
            pk0 = *(const f16x8*)(kh + (kbase + srow0) * HDd + sc8 * 8);
            pk1 = *(const f16x8*)(kh + (kbase + srow1) * HDd + sc8 * 8);
            pv0 = *(const f16x8*)(vt + ((size_t)bh * HDd + srow0) * Ss + kb_nxt * 64 + sc8 * 8);
            pv1 = *(const f16x8*)(vt + ((size_t)bh * HDd + srow1) * Ss + kb_nxt * 64 + sc8 * 8);
        }
        const char* Kc = smem + (cur ? 8192 : 0);
        const char* Vc = smem + 16384 + (cur ? 8192 : 0);

        // ---- mask mode (block-uniform): 0 none, 1 causal, 2 anti; skip ------
        int mm = 0;
        bool skip = false;
        if (t == 0 || t == NT - 1) mm = 1;                 // kb == qb: diagonal causal
        else if (t < 16) { if (kb_cur > qb) skip = true; } // garbage sel (qb<16)
        else if (W0 == 0 && t == 16) mm = 2;               // kb == qb-8: anti j>r

        if (!skip) {
            // ---- swapped QK^T + exp2 softmax-lite ---------------------------
            f16x8 pa8[2];
#pragma unroll
            for (int kt = 0; kt < 4; ++kt) {
                int krow = kt * 16 + lr;
                f16x8 kb0 = *(const f16x8*)(Kc + swz(krow, krow * 128 + lg * 16));
                f16x8 kb1 = *(const f16x8*)(Kc + swz(krow, krow * 128 + lg * 16 + 64));
                f32x4 c = (f32x4){0.f, 0.f, 0.f, 0.f};
                c = __builtin_amdgcn_mfma_f32_16x16x32_f16(kb0, qf0, c, 0, 0, 0);
                c = __builtin_amdgcn_mfma_f32_16x16x32_f16(kb1, qf1, c, 0, 0, 0);
#pragma unroll
                for (int rg = 0; rg < 4; ++rg) {
                    float sc = c[rg];
                    if (mm == 1) {
                        if (kt * 16 + 4 * lg + rg > w * 16 + lr) sc = NEGF;
                    } else if (mm == 2) {
                        if (kt * 16 + 4 * lg + rg <= w * 16 + lr) sc = NEGF;
                    }
                    float p = fexp2(sc);
                    pa8[kt >> 1][(kt & 1) * 4 + rg] = (_Float16)p;
                }
            }
            // row-sum denominators on the matrix pipe (rows match oacc's rows)
            oacc5 = __builtin_amdgcn_mfma_f32_16x16x32_f16(pa8[0], kone, oacc5, 0, 0, 0);
            oacc5 = __builtin_amdgcn_mfma_f32_16x16x32_f16(pa8[1], kone, oacc5, 0, 0, 0);

            // ---- PV: quad-interleaved V^T, b128 conflict-free ---------------
#pragma unroll
            for (int dt = 0; dt < 4; ++dt) {
                int vrow = dt * 16 + lr;
#pragma unroll
                for (int ktp = 0; ktp < 2; ++ktp) {
                    f16x8 vb = *(const f16x8*)(Vc + swz(vrow, vrow * 128 + ktp * 64 + lg * 16));
                    oacc[dt] = __builtin_amdgcn_mfma_f32_16x16x32_f16(pa8[ktp], vb, oacc[dt], 0, 0, 0);
                }
            }
        }

        // ---- phase boundary: snapshot selected result, reset ----------------
        if (t == 15) {
#pragma unroll
            for (int rg = 0; rg < 4; ++rg) {
                float inv = 1.f / oacc5[rg];
#pragma unroll
                for (int dt = 0; dt < 4; ++dt) osel[dt][rg] = oacc[dt][rg] * inv;
            }
#pragma unroll
            for (int dt = 0; dt < 4; ++dt) oacc[dt] = (f32x4){0.f, 0.f, 0.f, 0.f};
            oacc5 = (f32x4){0.f, 0.f, 0.f, 0.f};
        }

        // ---- write prefetched tile into the other buffer --------------------
        if (hasNext) {
            char* Kn = smem + (cur ? 0 : 8192);
            char* Vn = smem + 16384 + (cur ? 0 : 8192);
            *(f16x8*)(Kn + swz(srow0, srow0 * 128 + sc8 * 16)) = pk0;
            *(f16x8*)(Kn + swz(srow1, srow1 * 128 + sc8 * 16)) = pk1;
            STAGE_V(Vn, pv0, srow0, sc8);
            STAGE_V(Vn, pv1, srow1, sc8);
        }
        __syncthreads();
        cur ^= 1;
        kb_cur = kb_nxt;
    }

    // ---- epilogue: combine phases, gate, single coalesced RMW ---------------
    float* Os = (float*)smem;
#pragma unroll
    for (int rg = 0; rg < 4; ++rg) {
        float inv = 1.f / oacc5[rg];
        int row = w * 16 + 4 * lg + rg;
        int sq = q0 + row;
        float g1 = g[((size_t)(b * Ss + sq)) * 3 + 1];
        float g2 = g[((size_t)(b * Ss + sq)) * 3 + 2];
#pragma unroll
        for (int dt = 0; dt < 4; ++dt)
            Os[row * 68 + dt * 16 + lr] = g1 * osel[dt][rg] + g2 * oacc[dt][rg] * inv;
    }
    __syncthreads();
    {
        int row = tid >> 2;
        int c0 = (tid & 3) * 16;
        int s = q0 + row;
        float* op = o + ((size_t)(b * Ss + s)) * DMm + h * HDd + c0;
#pragma unroll
        for (int j = 0; j < 4; ++j) {
            float4 val = *(const float4*)&Os[row * 68 + c0 + j * 4];
            float4 cur4 = *(const float4*)&op[j * 4];
            cur4.x += val.x; cur4.y += val.y;
            cur4.z += val.z; cur4.w += val.w;
            *(float4*)&op[j * 4] = cur4;
        }
    }
}

// -------------------- constant emitter (host-side contract checks) ------------
__global__ __launch_bounds__(256) void k_const(float* __restrict__ y, float val)
{
    int i = blockIdx.x * 256 + threadIdx.x;
    y[i] = val;
}

// -------------------- launch --------------------------------------------------
extern "C" void kernel_launch(void* const* d_in, const int* in_sizes, int n_in,
                              void* d_out, int out_size, void* d_ws, size_t ws_size,
                              hipStream_t stream) {
    float* y = (float*)d_out;
    if (n_in != 6) {
        k_const<<<dim3(16384), 256, 0, stream>>>(y, 88888.f);
        return;
    }
    if (in_sizes[0] != 4194304 || in_sizes[1] != 262144 || in_sizes[2] != 262144 ||
        in_sizes[3] != 262144 || in_sizes[4] != 262144 || in_sizes[5] != 1536) {
        k_const<<<dim3(16384), 256, 0, stream>>>(y, 77777.f);
        return;
    }
    if (ws_size < WS_FLOATS * sizeof(float)) {
        k_const<<<dim3(16384), 256, 0, stream>>>(y, 66666.f);
        return;
    }

    const float* x  = (const float*)d_in[0];
    const float* Wq = (const float*)d_in[1];
    const float* Wk = (const float*)d_in[2];
    const float* Wv = (const float*)d_in[3];
    const float* Wo = (const float*)d_in[4];
    const float* Wg = (const float*)d_in[5];
    float* ws = (float*)d_ws;

    float* ow   = ws + OFF_O;
    float* gw   = ws + OFF_G;
    int*   selw = (int*)(ws + OFF_SEL);
    f16*   qhw  = (f16*)(ws + OFF_QH);
    f16*   qlw  = (f16*)(ws + OFF_QL);
    f16*   khw  = (f16*)(ws + OFF_KH);
    f16*   klw  = (f16*)(ws + OFF_KL);
    f16*   vtw  = (f16*)(ws + OFF_VT);
    f16*   kchw = (f16*)(ws + OFF_KCH);
    f16*   kclw = (f16*)(ws + OFF_KCL);
    f16*   vctw = (f16*)(ws + OFF_VCT);
    f16*   xhw  = (f16*)(ws + OFF_XH);   // aliases o region (freed before k_cmp)
    f16*   xlw  = (f16*)(ws + OFF_XL);
    f16*   wqh  = (f16*)(ws + OFF_WT);
    f16*   wql  = (f16*)(ws + OFF_WT + 131072);
    f16*   wkh  = (f16*)(ws + OFF_WT + 262144);
    f16*   wkl  = (f16*)(ws + OFF_WT + 393216);
    f16*   wvh  = (f16*)(ws + OFF_WT + 524288);
    f16*   wvl  = (f16*)(ws + OFF_WT + 655360);
    f16*   woh  = (f16*)(ws + OFF_WT + 786432);

    k_prep_xg<<<dim3(2048), 256, 0, stream>>>(x, Wg, xhw, xlw, gw);
    k_prep_w<<<dim3(8, 8, 4), 256, 0, stream>>>(Wq, Wk, Wv, Wo,
            wqh, wql, wkh, wkl, wvh, wvl, woh);
    k_gemm3<<<dim3(64, 8, 3), 256, 0, stream>>>(xhw, xlw,
            wqh, wql, wkh, wkl, wvh, qhw, qlw, khw, klw, vtw);
    k_pool<<<dim3(512), 256, 0, stream>>>(khw, klw, vtw, kchw, kclw, vctw);
    k_cmp<<<dim3(64, 16), 256, 0, stream>>>(qhw, qlw, kchw, kclw, vctw, gw, selw, ow);
    k_attn2<<<dim3(64, 16), 256, 0, stream>>>(qhw, khw, vtw, selw, gw, ow);
    k_outproj<<<dim3(64, 8), 256, 0, stream>>>(ow, woh, y);
}

// Round 14
// 233.468 us; speedup vs baseline: 2.5169x; 1.0854x over previous
//
#include <hip/hip_runtime.h>

// Problem constants
#define Hh    8
#define DMm   512
#define HDd   64
#define CBc   32
#define SBs   64
#define WINSZ 512
#define TOPKk 16
#define NEGF  (-1e30f)
#define Bb    2
#define Ss    4096
#define NCc   128   // S/CB
#define NSs   64    // S/SB
#define SCALE 0.125f
#define PSC   0.18033688011112042f   // SCALE * log2(e): q pre-scale -> exp2 softmax

// Workspace layout (float offsets)
#define OFF_KL   ((size_t)4194304)    // f16 k_lo [bh][s][d]
#define OFF_O    ((size_t)12582912)   // ALIASED: x_hi/x_lo live here until k_cmp writes o
#define OFF_G    ((size_t)16777216)   // B*S*3 = 24576
#define OFF_KC   ((size_t)16801792)   // kc_hi/kc_lo f16 (2 x 131072 halves)
#define OFF_VC   ((size_t)16932864)   // vc^T f16 (131072 halves)
#define OFF_IMPB ((size_t)17063936)   // (unused; kept for layout stability)
#define OFF_SEL  ((size_t)17129472)   // B*H*NS*TOPK ints = 16384
#define OFF_QH   ((size_t)17145856)   // f16 q  [bh][s][d] (pre-scaled by PSC)
#define OFF_KH   ((size_t)19243008)   // f16 k_hi [bh][s][d]
#define OFF_VT   ((size_t)21340160)   // f16 v^T [bh][d][s]
#define OFF_WT   ((size_t)23437312)   // 7 x 131072 floats of f16 W^T (hi/lo)
#define OFF_QL   ((size_t)24354816)   // f16 q_lo [bh][s][d] (pre-scaled by PSC)
#define WS_FLOATS ((size_t)25403392)

// x_hi/x_lo alias the o region (o first written by k_cmp, after GEMMs)
#define OFF_XH   (OFF_O)
#define OFF_XL   (OFF_O + 2097152)

#define OFF_KCH  (OFF_KC)
#define OFF_KCL  (OFF_KC + 65536)
#define OFF_VCT  (OFF_VC)

typedef _Float16 f16;
typedef _Float16 f16x4 __attribute__((ext_vector_type(4)));
typedef _Float16 f16x8 __attribute__((ext_vector_type(8)));
typedef float    f32x4 __attribute__((ext_vector_type(4)));

__device__ __forceinline__ int swz(int row, int byteoff) {
    return byteoff ^ ((row & 7) << 4);   // spreads stride-128B rows across banks
}
__device__ __forceinline__ float fexp2(float x) {
    return __builtin_amdgcn_exp2f(x);    // v_exp_f32: D = 2^S0
}

// V LDS layout: per 32-key block, quads interleaved as {4lg, 16+4lg} so that a
// single b128 read at [ktp*64 + lg*16] yields keys {ktp*32+4lg+0..3, +16+0..3}
// (matches in-register P order for mfma_16x16x32). Write side: 2 x b64.
#define STAGE_V(Vbase, vd, row, c8) do {                                     \
    int q0_ = ((c8) & 3) * 2, q1_ = q0_ + 1;                                 \
    int col0_ = ((c8) >> 2) * 64 + (q0_ & 3) * 16 + (q0_ >> 2) * 8;          \
    int col1_ = ((c8) >> 2) * 64 + (q1_ & 3) * 16 + (q1_ >> 2) * 8;          \
    f16x4 lo_ = { (vd)[0], (vd)[1], (vd)[2], (vd)[3] };                      \
    f16x4 hi_ = { (vd)[4], (vd)[5], (vd)[6], (vd)[7] };                      \
    *(f16x4*)((Vbase) + swz(row, (row) * 128 + col0_)) = lo_;                \
    *(f16x4*)((Vbase) + swz(row, (row) * 128 + col1_)) = hi_;                \
} while (0)

// -------------------- K0: fused {x -> x_hi/x_lo + gate} | {W -> W^T hi/lo} ----
// blocks [0,2048): wave-per-row x split + gate; blocks [2048,2304): W transpose.
__global__ __launch_bounds__(256) void k_prep(const float* __restrict__ x,
        const float* __restrict__ Wg,
        const float* __restrict__ Wq, const float* __restrict__ Wk,
        const float* __restrict__ Wv, const float* __restrict__ Wo,
        f16* __restrict__ xh, f16* __restrict__ xl, float* __restrict__ g,
        f16* __restrict__ wqh, f16* __restrict__ wql,
        f16* __restrict__ wkh, f16* __restrict__ wkl,
        f16* __restrict__ wvh, f16* __restrict__ wvl,
        f16* __restrict__ woh)
{
    __shared__ float T[64][68];
    const int tid = threadIdx.x;
    if (blockIdx.x < 2048) {
        const int w = tid >> 6, l = tid & 63;
        const int row = blockIdx.x * 4 + w;        // 0..8191
        const int d0 = l * 8;
        const float* xr = x + (size_t)row * DMm + d0;
        float4 a = *(const float4*)(xr);
        float4 b = *(const float4*)(xr + 4);
        float xv[8] = { a.x, a.y, a.z, a.w, b.x, b.y, b.z, b.w };
        f16x8 h, lo;
#pragma unroll
        for (int j = 0; j < 8; ++j) {
            h[j] = (_Float16)xv[j];
            lo[j] = (_Float16)(xv[j] - (float)h[j]);
        }
        size_t base = (size_t)row * DMm + d0;
        *(f16x8*)(xh + base) = h;
        *(f16x8*)(xl + base) = lo;
        float s0 = 0.f, s1 = 0.f, s2 = 0.f;
#pragma unroll
        for (int j = 0; j < 8; ++j) {
            const float* wr = Wg + (size_t)(d0 + j) * 3;
            s0 += xv[j] * wr[0];
            s1 += xv[j] * wr[1];
            s2 += xv[j] * wr[2];
        }
#pragma unroll
        for (int off = 1; off < 64; off <<= 1) {
            s0 += __shfl_xor(s0, off);
            s1 += __shfl_xor(s1, off);
            s2 += __shfl_xor(s2, off);
        }
        if (l == 0) {
            g[(size_t)row * 3 + 0] = 1.f / (1.f + expf(-s0));
            g[(size_t)row * 3 + 1] = 1.f / (1.f + expf(-s1));
            g[(size_t)row * 3 + 2] = 1.f / (1.f + expf(-s2));
        }
        return;
    }
    // ---- W-transpose path ---------------------------------------------------
    const int bid2 = blockIdx.x - 2048;   // 0..255
    const int k0 = (bid2 & 7) * 64;
    const int n0 = ((bid2 >> 3) & 7) * 64;
    const int z = bid2 >> 6;
    const float* W = (z == 0) ? Wq : ((z == 1) ? Wk : ((z == 2) ? Wv : Wo));
    f16* dh = (z == 0) ? wqh : ((z == 1) ? wkh : ((z == 2) ? wvh : woh));
    f16* dl = (z == 0) ? wql : ((z == 1) ? wkl : ((z == 2) ? wvl : (f16*)0));
    {
        int r = tid >> 2;
        int c16 = (tid & 3) * 16;
#pragma unroll
        for (int j = 0; j < 4; ++j) {
            float4 w4 = *(const float4*)(W + (size_t)(k0 + r) * DMm + n0 + c16 + j * 4);
            *(float4*)&T[r][c16 + j * 4] = w4;
        }
    }
    __syncthreads();
    {
        int n = tid >> 2;
        int k16 = (tid & 3) * 16;
        f16x8 h0, h1, l0, l1;
#pragma unroll
        for (int j = 0; j < 8; ++j) {
            float wv = T[k16 + j][n];
            h0[j] = (_Float16)wv; l0[j] = (_Float16)(wv - (float)h0[j]);
        }
#pragma unroll
        for (int j = 0; j < 8; ++j) {
            float wv = T[k16 + 8 + j][n];
            h1[j] = (_Float16)wv; l1[j] = (_Float16)(wv - (float)h1[j]);
        }
        size_t o = (size_t)(n0 + n) * DMm + k0 + k16;
        *(f16x8*)(dh + o) = h0;
        *(f16x8*)(dh + o + 8) = h1;
        if (dl) { *(f16x8*)(dl + o) = l0; *(f16x8*)(dl + o + 8) = l1; }
    }
}

// -------------------- K1: merged q/k/v projection GEMMs -----------------------
__global__ __launch_bounds__(256) void k_gemm3(
        const f16* __restrict__ xh, const f16* __restrict__ xl,
        const f16* __restrict__ wqh, const f16* __restrict__ wql,
        const f16* __restrict__ wkh, const f16* __restrict__ wkl,
        const f16* __restrict__ wvh,
        f16* __restrict__ qh, f16* __restrict__ ql,
        f16* __restrict__ kh, f16* __restrict__ kl,
        f16* __restrict__ vt)
{
    const int z = blockIdx.z;
    const int m0 = blockIdx.x * 128;
    const int n0 = blockIdx.y * 64;
    const int tid = threadIdx.x;
    const int w = tid >> 6, l = tid & 63;
    const int lr = l & 15, lg = l >> 4;
    const int wm = w >> 1, wn = w & 1;

    __shared__ f16 As[2][128 * 40];
    __shared__ f16 Bs[2][64 * 40];

    f32x4 acc[4][2];
#pragma unroll
    for (int mf = 0; mf < 4; ++mf)
#pragma unroll
        for (int nf = 0; nf < 2; ++nf) acc[mf][nf] = (f32x4){0.f, 0.f, 0.f, 0.f};

    const int ar = tid >> 1, ac = (tid & 1) * 16;
    const int bn = tid >> 2, bc = (tid & 3) * 8;

    if (z == 2) {
        // ---- v path: plain f16, swapped-operand MFMA -> transposed out ------
        for (int k0 = 0; k0 < DMm; k0 += 32) {
            {
                const f16* src = xh + (size_t)(m0 + ar) * DMm + k0 + ac;
                *(f16x8*)&As[0][ar * 40 + ac] = *(const f16x8*)src;
                *(f16x8*)&As[0][ar * 40 + ac + 8] = *(const f16x8*)(src + 8);
                const f16* srcb = wvh + (size_t)(n0 + bn) * DMm + k0 + bc;
                *(f16x8*)&Bs[0][bn * 40 + bc] = *(const f16x8*)srcb;
            }
            __syncthreads();
            f16x8 ahf[4], bhf[2];
#pragma unroll
            for (int mf = 0; mf < 4; ++mf)
                ahf[mf] = *(const f16x8*)&As[0][(wm * 64 + mf * 16 + lr) * 40 + lg * 8];
#pragma unroll
            for (int nf = 0; nf < 2; ++nf)
                bhf[nf] = *(const f16x8*)&Bs[0][(wn * 32 + nf * 16 + lr) * 40 + lg * 8];
#pragma unroll
            for (int mf = 0; mf < 4; ++mf)
#pragma unroll
                for (int nf = 0; nf < 2; ++nf)
                    acc[mf][nf] = __builtin_amdgcn_mfma_f32_16x16x32_f16(bhf[nf], ahf[mf], acc[mf][nf], 0, 0, 0);
            __syncthreads();
        }
        const int h = n0 >> 6;
#pragma unroll
        for (int mf = 0; mf < 4; ++mf)
#pragma unroll
            for (int nf = 0; nf < 2; ++nf)
#pragma unroll
                for (int rg = 0; rg < 4; ++rg) {
                    int n = n0 + wn * 32 + nf * 16 + 4 * lg + rg;   // d (global)
                    int m = m0 + wm * 64 + mf * 16 + lr;            // s (incl batch)
                    int b = m >> 12, s = m & 4095;
                    vt[(((size_t)(b * Hh + h)) * HDd + (n & 63)) * Ss + s] =
                        (f16)acc[mf][nf][rg];
                }
        return;
    }

    // ---- q/k path: split-f16 (3-product, fp32-grade) ------------------------
    const f16* Bh = z ? wkh : wqh;
    const f16* Bl = z ? wkl : wql;
    f16* Ch = z ? kh : qh;
    f16* Cl = z ? kl : ql;
    const float cscale = z ? 1.f : PSC;

    for (int k0 = 0; k0 < DMm; k0 += 32) {
        {
            const f16* src = xh + (size_t)(m0 + ar) * DMm + k0 + ac;
            *(f16x8*)&As[0][ar * 40 + ac] = *(const f16x8*)src;
            *(f16x8*)&As[0][ar * 40 + ac + 8] = *(const f16x8*)(src + 8);
            const f16* src2 = xl + (size_t)(m0 + ar) * DMm + k0 + ac;
            *(f16x8*)&As[1][ar * 40 + ac] = *(const f16x8*)src2;
            *(f16x8*)&As[1][ar * 40 + ac + 8] = *(const f16x8*)(src2 + 8);
        }
        {
            const f16* src = Bh + (size_t)(n0 + bn) * DMm + k0 + bc;
            *(f16x8*)&Bs[0][bn * 40 + bc] = *(const f16x8*)src;
            const f16* src2 = Bl + (size_t)(n0 + bn) * DMm + k0 + bc;
            *(f16x8*)&Bs[1][bn * 40 + bc] = *(const f16x8*)src2;
        }
        __syncthreads();

        f16x8 ahf[4], alf[4], bhf[2], blf[2];
#pragma unroll
        for (int mf = 0; mf < 4; ++mf) {
            int row = wm * 64 + mf * 16 + lr;
            ahf[mf] = *(const f16x8*)&As[0][row * 40 + lg * 8];
            alf[mf] = *(const f16x8*)&As[1][row * 40 + lg * 8];
        }
#pragma unroll
        for (int nf = 0; nf < 2; ++nf) {
            int row = wn * 32 + nf * 16 + lr;
            bhf[nf] = *(const f16x8*)&Bs[0][row * 40 + lg * 8];
            blf[nf] = *(const f16x8*)&Bs[1][row * 40 + lg * 8];
        }
#pragma unroll
        for (int mf = 0; mf < 4; ++mf)
#pragma unroll
            for (int nf = 0; nf < 2; ++nf) {
                acc[mf][nf] = __builtin_amdgcn_mfma_f32_16x16x32_f16(ahf[mf], bhf[nf], acc[mf][nf], 0, 0, 0);
                acc[mf][nf] = __builtin_amdgcn_mfma_f32_16x16x32_f16(ahf[mf], blf[nf], acc[mf][nf], 0, 0, 0);
                acc[mf][nf] = __builtin_amdgcn_mfma_f32_16x16x32_f16(alf[mf], bhf[nf], acc[mf][nf], 0, 0, 0);
            }
        __syncthreads();
    }

#pragma unroll
    for (int mf = 0; mf < 4; ++mf)
#pragma unroll
        for (int nf = 0; nf < 2; ++nf)
#pragma unroll
            for (int rg = 0; rg < 4; ++rg) {
                int m = m0 + wm * 64 + mf * 16 + 4 * lg + rg;
                int n = n0 + wn * 32 + nf * 16 + lr;
                int b = m >> 12, s = m & 4095;
                int h = n >> 6, d = n & 63;
                size_t o = (((size_t)(b * Hh + h)) * Ss + s) * HDd + d;
                float vs = acc[mf][nf][rg] * cscale;
                f16 hv = (f16)vs;
                Ch[o] = hv;
                Cl[o] = (f16)(vs - (float)hv);
            }
}

// -------------------- K1c: outproj GEMM (fp32 A staged, plain f16) ------------
__global__ __launch_bounds__(256) void k_outproj(const float* __restrict__ Af,
        const f16* __restrict__ Bh, float* __restrict__ Cf)
{
    const int m0 = blockIdx.x * 128;
    const int n0 = blockIdx.y * 64;
    const int tid = threadIdx.x;
    const int w = tid >> 6, l = tid & 63;
    const int lr = l & 15, lg = l >> 4;
    const int wm = w >> 1, wn = w & 1;

    __shared__ f16 As[128 * 40];
    __shared__ f16 Bs[64 * 40];

    f32x4 acc[4][2];
#pragma unroll
    for (int mf = 0; mf < 4; ++mf)
#pragma unroll
        for (int nf = 0; nf < 2; ++nf) acc[mf][nf] = (f32x4){0.f, 0.f, 0.f, 0.f};

    const int ar = tid >> 1, ac = (tid & 1) * 16;
    const int bn = tid >> 2, bc = (tid & 3) * 8;

    for (int k0 = 0; k0 < DMm; k0 += 32) {
        {
            const float* src = Af + (size_t)(m0 + ar) * DMm + k0 + ac;
            float4 a0 = *(const float4*)(src);
            float4 a1 = *(const float4*)(src + 4);
            float4 a2 = *(const float4*)(src + 8);
            float4 a3 = *(const float4*)(src + 12);
            f16x8 h0, h1;
            h0[0] = (_Float16)a0.x; h0[1] = (_Float16)a0.y; h0[2] = (_Float16)a0.z; h0[3] = (_Float16)a0.w;
            h0[4] = (_Float16)a1.x; h0[5] = (_Float16)a1.y; h0[6] = (_Float16)a1.z; h0[7] = (_Float16)a1.w;
            h1[0] = (_Float16)a2.x; h1[1] = (_Float16)a2.y; h1[2] = (_Float16)a2.z; h1[3] = (_Float16)a2.w;
            h1[4] = (_Float16)a3.x; h1[5] = (_Float16)a3.y; h1[6] = (_Float16)a3.z; h1[7] = (_Float16)a3.w;
            *(f16x8*)&As[ar * 40 + ac] = h0;
            *(f16x8*)&As[ar * 40 + ac + 8] = h1;
            const f16* srcb = Bh + (size_t)(n0 + bn) * DMm + k0 + bc;
            *(f16x8*)&Bs[bn * 40 + bc] = *(const f16x8*)srcb;
        }
        __syncthreads();
        f16x8 ahf[4], bhf[2];
#pragma unroll
        for (int mf = 0; mf < 4; ++mf)
            ahf[mf] = *(const f16x8*)&As[(wm * 64 + mf * 16 + lr) * 40 + lg * 8];
#pragma unroll
        for (int nf = 0; nf < 2; ++nf)
            bhf[nf] = *(const f16x8*)&Bs[(wn * 32 + nf * 16 + lr) * 40 + lg * 8];
#pragma unroll
        for (int mf = 0; mf < 4; ++mf)
#pragma unroll
            for (int nf = 0; nf < 2; ++nf)
                acc[mf][nf] = __builtin_amdgcn_mfma_f32_16x16x32_f16(ahf[mf], bhf[nf], acc[mf][nf], 0, 0, 0);
        __syncthreads();
    }
#pragma unroll
    for (int mf = 0; mf < 4; ++mf)
#pragma unroll
        for (int nf = 0; nf < 2; ++nf)
#pragma unroll
            for (int rg = 0; rg < 4; ++rg) {
                int m = m0 + wm * 64 + mf * 16 + 4 * lg + rg;
                int n = n0 + wn * 32 + nf * 16 + lr;
                Cf[(size_t)m * DMm + n] = acc[mf][nf][rg];
            }
}

// -------------------- K3: mean-pool from f16 k_hi/k_lo and vt -----------------
__global__ __launch_bounds__(256) void k_pool(const f16* __restrict__ kh,
        const f16* __restrict__ kl, const f16* __restrict__ vt,
        f16* __restrict__ kch, f16* __restrict__ kcl, f16* __restrict__ vct)
{
    int idx = blockIdx.x * 256 + threadIdx.x;  // B*H*NC*HD = 131072
    int bh = idx >> 13;
    {
        int d = idx & 63;
        int n = (idx >> 6) & 127;
        const f16* kp = kh + ((size_t)bh * Ss + n * CBc) * HDd + d;
        const f16* lp = kl + ((size_t)bh * Ss + n * CBc) * HDd + d;
        float sk = 0.f;
        for (int t = 0; t < CBc; ++t)
            sk += (float)kp[(size_t)t * HDd] + (float)lp[(size_t)t * HDd];
        float mk = sk * (1.f / CBc);
        f16 h = (f16)mk;
        kch[idx] = h;
        kcl[idx] = (f16)(mk - (float)h);
    }
    {
        int vd = (idx >> 7) & 63;
        int vn = idx & 127;
        const f16* vp = vt + ((size_t)bh * HDd + vd) * Ss + vn * CBc;
        float sv = 0.f;
#pragma unroll
        for (int j = 0; j < 4; ++j) {
            f16x8 v8 = *(const f16x8*)(vp + j * 8);
#pragma unroll
            for (int e = 0; e < 8; ++e) sv += (float)v8[e];
        }
        vct[((size_t)bh * HDd + vd) * NCc + vn] = (f16)(sv * (1.f / CBc));
    }
}

// -------------------- K4: compressed attention + importance + FUSED top-k -----
__global__ __launch_bounds__(256) void k_cmp(const f16* __restrict__ qh,
        const f16* __restrict__ ql, const f16* __restrict__ kch,
        const f16* __restrict__ kcl, const f16* __restrict__ vct,
        const float* __restrict__ g, int* __restrict__ sel, float* __restrict__ o)
{
    const int qb = blockIdx.x;   // 0..63
    const int bh = blockIdx.y;   // 0..15
    const int b = bh >> 3, h = bh & 7;
    const int q0 = qb * 64;
    const int tid = threadIdx.x;
    const int w = tid >> 6, l = tid & 63;
    const int lr = l & 15, lg = l >> 4;

    __shared__ __align__(16) char smem[51456];
    float* Pm = (float*)smem;                       // [64][132] fp32 exp2 values
    char* U = smem + 33792;                         // 16KB union: {KCh,KCl} / {VCt,Ps}
    float* red2 = (float*)(smem + 33792 + 16384);   // 256 floats
    float* rinv = (float*)(smem + 51200);           // 64 floats

    const int NCT = (qb <= 30) ? 1 : 2;
    const int ncols = NCT * 64;

    f16x8 qfh0, qfh1, qfl0, qfl1;
    {
        size_t qoff = ((size_t)bh * Ss + q0 + w * 16 + lr) * HDd + lg * 8;
        qfh0 = *(const f16x8*)(qh + qoff);
        qfh1 = *(const f16x8*)(qh + qoff + 32);
        qfl0 = *(const f16x8*)(ql + qoff);
        qfl1 = *(const f16x8*)(ql + qoff + 32);
    }

    for (int ct = 0; ct < NCT; ++ct) {
        __syncthreads();
#pragma unroll
        for (int p = 0; p < 2; ++p) {
            int idx = tid + p * 256;
            int row = idx >> 3;           // chunk 0..63
            int c8 = idx & 7;
            size_t src = ((size_t)bh * NCc + ct * 64 + row) * HDd + c8 * 8;
            *(f16x8*)(U + swz(row, row * 128 + c8 * 16)) = *(const f16x8*)(kch + src);
            *(f16x8*)(U + 8192 + swz(row, row * 128 + c8 * 16)) = *(const f16x8*)(kcl + src);
        }
        __syncthreads();
#pragma unroll
        for (int kt = 0; kt < 4; ++kt) {
            int krow = kt * 16 + lr;
            f16x8 bh0 = *(const f16x8*)(U + swz(krow, krow * 128 + lg * 16));
            f16x8 bh1 = *(const f16x8*)(U + swz(krow, krow * 128 + lg * 16 + 64));
            f16x8 bl0 = *(const f16x8*)(U + 8192 + swz(krow, krow * 128 + lg * 16));
            f16x8 bl1 = *(const f16x8*)(U + 8192 + swz(krow, krow * 128 + lg * 16 + 64));
            f32x4 c = (f32x4){0.f, 0.f, 0.f, 0.f};
            c = __builtin_amdgcn_mfma_f32_16x16x32_f16(qfh0, bh0, c, 0, 0, 0);
            c = __builtin_amdgcn_mfma_f32_16x16x32_f16(qfh1, bh1, c, 0, 0, 0);
            c = __builtin_amdgcn_mfma_f32_16x16x32_f16(qfh0, bl0, c, 0, 0, 0);
            c = __builtin_amdgcn_mfma_f32_16x16x32_f16(qfh1, bl1, c, 0, 0, 0);
            c = __builtin_amdgcn_mfma_f32_16x16x32_f16(qfl0, bh0, c, 0, 0, 0);
            c = __builtin_amdgcn_mfma_f32_16x16x32_f16(qfl1, bh1, c, 0, 0, 0);
            int n = ct * 64 + kt * 16 + lr;
#pragma unroll
            for (int rg = 0; rg < 4; ++rg) {
                int row = w * 16 + 4 * lg + rg;
                int s = q0 + row;
                bool valid = (32 * n + 31 <= s);
                Pm[row * 132 + n] = valid ? c[rg] : NEGF;   // log2-domain score
            }
        }
    }
    __syncthreads();

    {
        int r = tid >> 2;
        int l4 = tid & 3;
        float m = NEGF;
        for (int c = l4; c < ncols; c += 4) m = fmaxf(m, Pm[r * 132 + c]);
        m = fmaxf(m, __shfl_xor(m, 1));
        m = fmaxf(m, __shfl_xor(m, 2));
        float sum = 0.f;
        if (m > NEGF * 0.5f) {
            for (int c = l4; c < ncols; c += 4) {
                float sv = Pm[r * 132 + c];
                float p = (sv <= NEGF * 0.5f) ? 0.f : fexp2(sv - m);
                Pm[r * 132 + c] = p;    // unnormalized
                sum += p;
            }
        } else {
            for (int c = l4; c < ncols; c += 4) Pm[r * 132 + c] = 0.f;
        }
        sum += __shfl_xor(sum, 1);
        sum += __shfl_xor(sum, 2);
        if (l4 == 0) rinv[r] = (sum > 0.f) ? 1.f / sum : 0.f;
    }
    __syncthreads();

    {
        float part = 0.f;
#pragma unroll
        for (int rr = 0; rr < 16; ++rr) {
            int qq = w * 16 + rr;
            int c = 2 * l;
            if (c < ncols) {
                float2 pv2 = *(const float2*)&Pm[qq * 132 + c];
                part += (pv2.x + pv2.y) * rinv[qq];
            }
        }
        red2[w * 64 + l] = part;
    }
    __syncthreads();
    if (tid < 64) {
        float tot = red2[tid] + red2[64 + tid] + red2[128 + tid] + red2[192 + tid];
        // fused top-k (wave 0): identical values + tie-break as old k_topk
        int j = tid;
        float v = tot;
        if (j > qb) v = NEGF;
        if (j == qb) v += 1e9f;
        int* selrow = sel + ((size_t)bh * NSs + qb) * TOPKk;
        for (int t = 0; t < TOPKk; ++t) {
            float bv = v; int bi = j;
#pragma unroll
            for (int off = 1; off < 64; off <<= 1) {
                float ov = __shfl_xor(bv, off);
                int oi = __shfl_xor(bi, off);
                if (ov > bv || (ov == bv && oi < bi)) { bv = ov; bi = oi; }
            }
            if (tid == 0) selrow[t] = bi;
            if (j == bi) v = -3e38f;
        }
    }

    f32x4 oacc[4];
#pragma unroll
    for (int dt = 0; dt < 4; ++dt) oacc[dt] = (f32x4){0.f, 0.f, 0.f, 0.f};
    char* Ps = U + 8192 + w * 2048;
    for (int ct = 0; ct < NCT; ++ct) {
        __syncthreads();
#pragma unroll
        for (int p = 0; p < 2; ++p) {
            int idx = tid + p * 256;
            int row = idx >> 3;           // d 0..63
            int c8 = idx & 7;
            size_t src = ((size_t)bh * HDd + row) * NCc + ct * 64 + c8 * 8;
            *(f16x8*)(U + swz(row, row * 128 + c8 * 16)) = *(const f16x8*)(vct + src);
        }
        {
            int r = l >> 2;
            int c0 = (l & 3) * 16;
            float ri = rinv[w * 16 + r];
            const float* pr = &Pm[(w * 16 + r) * 132 + ct * 64 + c0];
            float4 p0 = *(const float4*)(pr);
            float4 p1 = *(const float4*)(pr + 4);
            float4 p2 = *(const float4*)(pr + 8);
            float4 p3 = *(const float4*)(pr + 12);
            f16x8 h0, h1;
            h0[0] = (_Float16)(p0.x * ri); h0[1] = (_Float16)(p0.y * ri);
            h0[2] = (_Float16)(p0.z * ri); h0[3] = (_Float16)(p0.w * ri);
            h0[4] = (_Float16)(p1.x * ri); h0[5] = (_Float16)(p1.y * ri);
            h0[6] = (_Float16)(p1.z * ri); h0[7] = (_Float16)(p1.w * ri);
            h1[0] = (_Float16)(p2.x * ri); h1[1] = (_Float16)(p2.y * ri);
            h1[2] = (_Float16)(p2.z * ri); h1[3] = (_Float16)(p2.w * ri);
            h1[4] = (_Float16)(p3.x * ri); h1[5] = (_Float16)(p3.y * ri);
            h1[6] = (_Float16)(p3.z * ri); h1[7] = (_Float16)(p3.w * ri);
            *(f16x8*)(Ps + swz(r, r * 128 + c0 * 2)) = h0;
            *(f16x8*)(Ps + swz(r, r * 128 + c0 * 2 + 16)) = h1;
        }
        __syncthreads();
        f16x8 pa0 = *(const f16x8*)(Ps + swz(lr, lr * 128 + lg * 16));
        f16x8 pa1 = *(const f16x8*)(Ps + swz(lr, lr * 128 + lg * 16 + 64));
#pragma unroll
        for (int dt = 0; dt < 4; ++dt) {
            int vrow = dt * 16 + lr;
            f16x8 vb0 = *(const f16x8*)(U + swz(vrow, vrow * 128 + lg * 16));
            f16x8 vb1 = *(const f16x8*)(U + swz(vrow, vrow * 128 + lg * 16 + 64));
            oacc[dt] = __builtin_amdgcn_mfma_f32_16x16x32_f16(pa0, vb0, oacc[dt], 0, 0, 0);
            oacc[dt] = __builtin_amdgcn_mfma_f32_16x16x32_f16(pa1, vb1, oacc[dt], 0, 0, 0);
        }
    }

#pragma unroll
    for (int rg = 0; rg < 4; ++rg) {
        int row = w * 16 + 4 * lg + rg;
        int s = q0 + row;
        float g0 = g[((size_t)(b * Ss + s)) * 3 + 0];
#pragma unroll
        for (int dt = 0; dt < 4; ++dt)
            o[((size_t)(b * Ss + s)) * DMm + h * HDd + dt * 16 + lr] = g0 * oacc[dt][rg];
    }
}

// -------------------- K6: merged MFMA attention (selected + window) -----------
// NSEL clamp: sel is sorted by importance and garbage (masked-NEGF) entries can
// only occupy the tail, so NSEL = min(16, qb+1) makes the selected loop exact --
// garbage tiles are never staged/barriered at all.
__global__ __launch_bounds__(256) void k_attn2(const f16* __restrict__ qh,
        const f16* __restrict__ kh, const f16* __restrict__ vt,
        const int* __restrict__ sel, const float* __restrict__ g,
        float* __restrict__ o)
{
    const int bid = blockIdx.x + 64 * blockIdx.y;   // 0..1023
    const int bh = ((bid & 7) << 1) | ((bid >> 3) & 1);
    const int qb = bid >> 4;
    const int b = bh >> 3, h = bh & 7;
    const int q0 = qb * 64;
    const int tid = threadIdx.x;
    const int w  = tid >> 6;      // wave 0..3
    const int l  = tid & 63;
    const int lr = l & 15;
    const int lg = l >> 4;

    __shared__ __align__(16) char smem[32768];
    // K dbuf: [0,8K) [8K,16K); V dbuf: [16K,24K) [24K,32K)

    f16x8 qf0, qf1;
    {
        const f16* qptr = qh + ((size_t)bh * Ss + q0 + w * 16 + lr) * HDd + lg * 8;
        qf0 = *(const f16x8*)(qptr);
        qf1 = *(const f16x8*)(qptr + 32);
    }
    f16x8 kone;
#pragma unroll
    for (int j = 0; j < 8; ++j) kone[j] = (_Float16)1.f;

    const int W0 = (qb < 8) ? (8 - qb) : 0;
    const int NSEL = (qb + 1 < TOPKk) ? (qb + 1) : TOPKk;   // garbage-free count
    const int NT = NSEL + 9 - W0;       // NSEL selected + (9-W0) window
    const int* selrow = sel + ((size_t)bh * NSs + qb) * TOPKk;

    f32x4 oacc[4], osel[4], oacc5;
#pragma unroll
    for (int dt = 0; dt < 4; ++dt) {
        oacc[dt] = (f32x4){0.f, 0.f, 0.f, 0.f};
        osel[dt] = (f32x4){0.f, 0.f, 0.f, 0.f};
    }
    oacc5 = (f32x4){0.f, 0.f, 0.f, 0.f};

    const int srow0 = tid >> 3, sc8 = tid & 7;
    const int srow1 = (tid + 256) >> 3;
    f16x8 pk0, pk1, pv0, pv1;

    // prologue: stage tile 0 into buf 0
    int kb_cur = __builtin_amdgcn_readfirstlane(selrow[0]);
    {
        size_t kbase = (size_t)bh * Ss + kb_cur * 64;
        pk0 = *(const f16x8*)(kh + (kbase + srow0) * HDd + sc8 * 8);
        pk1 = *(const f16x8*)(kh + (kbase + srow1) * HDd + sc8 * 8);
        pv0 = *(const f16x8*)(vt + ((size_t)bh * HDd + srow0) * Ss + kb_cur * 64 + sc8 * 8);
        pv1 = *(const f16x8*)(vt + ((size_t)bh * HDd + srow1) * Ss + kb_cur * 64 + sc8 * 8);
        *(f16x8*)(smem + swz(srow0, srow0 * 128 + sc8 * 16)) = pk0;
        *(f16x8*)(smem + swz(srow1, srow1 * 128 + sc8 * 16)) = pk1;
        STAGE_V(smem + 16384, pv0, srow0, sc8);
        STAGE_V(smem + 16384, pv1, srow1, sc8);
    }
    __syncthreads();

    int cur = 0;
    for (int t = 0; t < NT; ++t) {
        // ---- prefetch issue (next tile -> regs) -----------------------------
        int kb_nxt = 0;
        const bool hasNext = (t + 1 < NT);
        if (hasNext) {
            kb_nxt = (t + 1 < NSEL) ? __builtin_amdgcn_readfirstlane(selrow[t + 1])
                                    : (qb - 8 + W0 + (t + 1 - NSEL));
            size_t kbase = (size_t)bh * Ss + kb_nxt * 64;
            pk0 = *(const f16x8*)(kh + (kbase + srow0) * HDd + sc8 * 8);
            pk1 = *(const f16x8*)(kh + (kbase + srow1) * HDd + sc8 * 8);
            pv0 = *(const f16x8*)(vt + ((size_t)bh * HDd + srow0) * Ss + kb_nxt * 64 + sc8 * 8);
            pv1 = *(const f16x8*)(vt + ((size_t)bh * HDd + srow1) * Ss + kb_nxt * 64 + sc8 * 8);
        }
        const char* Kc = smem + (cur ? 8192 : 0);
        const char* Vc = smem + 16384 + (cur ? 8192 : 0);

        // ---- mask mode (block-uniform): 0 none, 1 causal, 2 anti ------------
        int mm = 0;
        if (t == 0 || t == NT - 1) mm = 1;            // kb == qb (sel head / win tail)
        else if (W0 == 0 && t == NSEL) mm = 2;        // kb == qb-8: anti j>r

        {
            // ---- swapped QK^T + exp2 softmax-lite ---------------------------
            f16x8 pa8[2];
#pragma unroll
            for (int kt = 0; kt < 4; ++kt) {
                int krow = kt * 16 + lr;
                f16x8 kb0 = *(const f16x8*)(Kc + swz(krow, krow * 128 + lg * 16));
                f16x8 kb1 = *(const f16x8*)(Kc + swz(krow, krow * 128 + lg * 16 + 64));
                f32x4 c = (f32x4){0.f, 0.f, 0.f, 0.f};
                c = __builtin_amdgcn_mfma_f32_16x16x32_f16(kb0, qf0, c, 0, 0, 0);
                c = __builtin_amdgcn_mfma_f32_16x16x32_f16(kb1, qf1, c, 0, 0, 0);
#pragma unroll
                for (int rg = 0; rg < 4; ++rg) {
                    float sc = c[rg];
                    if (mm == 1) {
                        if (kt * 16 + 4 * lg + rg > w * 16 + lr) sc = NEGF;
                    } else if (mm == 2) {
                        if (kt * 16 + 4 * lg + rg <= w * 16 + lr) sc = NEGF;
                    }
                    float p = fexp2(sc);
                    pa8[kt >> 1][(kt & 1) * 4 + rg] = (_Float16)p;
                }
            }
            // row-sum denominators on the matrix pipe (rows match oacc's rows)
            oacc5 = __builtin_amdgcn_mfma_f32_16x16x32_f16(pa8[0], kone, oacc5, 0, 0, 0);
            oacc5 = __builtin_amdgcn_mfma_f32_16x16x32_f16(pa8[1], kone, oacc5, 0, 0, 0);

            // ---- PV: quad-interleaved V^T, b128 conflict-free ---------------
#pragma unroll
            for (int dt = 0; dt < 4; ++dt) {
                int vrow = dt * 16 + lr;
#pragma unroll
                for (int ktp = 0; ktp < 2; ++ktp) {
                    f16x8 vb = *(const f16x8*)(Vc + swz(vrow, vrow * 128 + ktp * 64 + lg * 16));
                    oacc[dt] = __builtin_amdgcn_mfma_f32_16x16x32_f16(pa8[ktp], vb, oacc[dt], 0, 0, 0);
                }
            }
        }

        // ---- phase boundary: snapshot selected result, reset ----------------
        if (t == NSEL - 1) {
#pragma unroll
            for (int rg = 0; rg < 4; ++rg) {
                float inv = 1.f / oacc5[rg];
#pragma unroll
                for (int dt = 0; dt < 4; ++dt) osel[dt][rg] = oacc[dt][rg] * inv;
            }
#pragma unroll
            for (int dt = 0; dt < 4; ++dt) oacc[dt] = (f32x4){0.f, 0.f, 0.f, 0.f};
            oacc5 = (f32x4){0.f, 0.f, 0.f, 0.f};
        }

        // ---- write prefetched tile into the other buffer --------------------
        if (hasNext) {
            char* Kn = smem + (cur ? 0 : 8192);
            char* Vn = smem + 16384 + (cur ? 0 : 8192);
            *(f16x8*)(Kn + swz(srow0, srow0 * 128 + sc8 * 16)) = pk0;
            *(f16x8*)(Kn + swz(srow1, srow1 * 128 + sc8 * 16)) = pk1;
            STAGE_V(Vn, pv0, srow0, sc8);
            STAGE_V(Vn, pv1, srow1, sc8);
        }
        __syncthreads();
        cur ^= 1;
        kb_cur = kb_nxt;
    }

    // ---- epilogue: combine phases, gate, single coalesced RMW ---------------
    float* Os = (float*)smem;
#pragma unroll
    for (int rg = 0; rg < 4; ++rg) {
        float inv = 1.f / oacc5[rg];
        int row = w * 16 + 4 * lg + rg;
        int sq = q0 + row;
        float g1 = g[((size_t)(b * Ss + sq)) * 3 + 1];
        float g2 = g[((size_t)(b * Ss + sq)) * 3 + 2];
#pragma unroll
        for (int dt = 0; dt < 4; ++dt)
            Os[row * 68 + dt * 16 + lr] = g1 * osel[dt][rg] + g2 * oacc[dt][rg] * inv;
    }
    __syncthreads();
    {
        int row = tid >> 2;
        int c0 = (tid & 3) * 16;
        int s = q0 + row;
        float* op = o + ((size_t)(b * Ss + s)) * DMm + h * HDd + c0;
#pragma unroll
        for (int j = 0; j < 4; ++j) {
            float4 val = *(const float4*)&Os[row * 68 + c0 + j * 4];
            float4 cur4 = *(const float4*)&op[j * 4];
            cur4.x += val.x; cur4.y += val.y;
            cur4.z += val.z; cur4.w += val.w;
            *(float4*)&op[j * 4] = cur4;
        }
    }
}

// -------------------- constant emitter (host-side contract checks) ------------
__global__ __launch_bounds__(256) void k_const(float* __restrict__ y, float val)
{
    int i = blockIdx.x * 256 + threadIdx.x;
    y[i] = val;
}

// -------------------- launch --------------------------------------------------
extern "C" void kernel_launch(void* const* d_in, const int* in_sizes, int n_in,
                              void* d_out, int out_size, void* d_ws, size_t ws_size,
                              hipStream_t stream) {
    float* y = (float*)d_out;
    if (n_in != 6) {
        k_const<<<dim3(16384), 256, 0, stream>>>(y, 88888.f);
        return;
    }
    if (in_sizes[0] != 4194304 || in_sizes[1] != 262144 || in_sizes[2] != 262144 ||
        in_sizes[3] != 262144 || in_sizes[4] != 262144 || in_sizes[5] != 1536) {
        k_const<<<dim3(16384), 256, 0, stream>>>(y, 77777.f);
        return;
    }
    if (ws_size < WS_FLOATS * sizeof(float)) {
        k_const<<<dim3(16384), 256, 0, stream>>>(y, 66666.f);
        return;
    }

    const float* x  = (const float*)d_in[0];
    const float* Wq = (const float*)d_in[1];
    const float* Wk = (const float*)d_in[2];
    const float* Wv = (const float*)d_in[3];
    const float* Wo = (const float*)d_in[4];
    const float* Wg = (const float*)d_in[5];
    float* ws = (float*)d_ws;

    float* ow   = ws + OFF_O;
    float* gw   = ws + OFF_G;
    int*   selw = (int*)(ws + OFF_SEL);
    f16*   qhw  = (f16*)(ws + OFF_QH);
    f16*   qlw  = (f16*)(ws + OFF_QL);
    f16*   khw  = (f16*)(ws + OFF_KH);
    f16*   klw  = (f16*)(ws + OFF_KL);
    f16*   vtw  = (f16*)(ws + OFF_VT);
    f16*   kchw = (f16*)(ws + OFF_KCH);
    f16*   kclw = (f16*)(ws + OFF_KCL);
    f16*   vctw = (f16*)(ws + OFF_VCT);
    f16*   xhw  = (f16*)(ws + OFF_XH);   // aliases o region (freed before k_cmp)
    f16*   xlw  = (f16*)(ws + OFF_XL);
    f16*   wqh  = (f16*)(ws + OFF_WT);
    f16*   wql  = (f16*)(ws + OFF_WT + 131072);
    f16*   wkh  = (f16*)(ws + OFF_WT + 262144);
    f16*   wkl  = (f16*)(ws + OFF_WT + 393216);
    f16*   wvh  = (f16*)(ws + OFF_WT + 524288);
    f16*   wvl  = (f16*)(ws + OFF_WT + 655360);
    f16*   woh  = (f16*)(ws + OFF_WT + 786432);

    k_prep<<<dim3(2304), 256, 0, stream>>>(x, Wg, Wq, Wk, Wv, Wo,
            xhw, xlw, gw, wqh, wql, wkh, wkl, wvh, wvl, woh);
    k_gemm3<<<dim3(64, 8, 3), 256, 0, stream>>>(xhw, xlw,
            wqh, wql, wkh, wkl, wvh, qhw, qlw, khw, klw, vtw);
    k_pool<<<dim3(512), 256, 0, stream>>>(khw, klw, vtw, kchw, kclw, vctw);
    k_cmp<<<dim3(64, 16), 256, 0, stream>>>(qhw, qlw, kchw, kclw, vctw, gw, selw, ow);
    k_attn2<<<dim3(64, 16), 256, 0, stream>>>(qhw, khw, vtw, selw, gw, ow);
    k_outproj<<<dim3(64, 8), 256, 0, stream>>>(ow, woh, y);
}